// Round 6
// baseline (570.278 us; speedup 1.0000x reference)
//
#include <hip/hip_runtime.h>
#include <hip/hip_bf16.h>
#include <math.h>

#define B_SZ 512
#define SEQ 3
#define D_MODEL 1550
#define ED 3100
#define NSTATE 16
#define DTR 97
#define DBC_R 129   // DTR + 2*NSTATE
#define VOCAB 128
#define NBS (B_SZ*SEQ)       // 1536
#define EPSV 1e-5f

// padded dims
#define KD 1600     // D_MODEL -> 64*25
#define KE 3136     // ED -> 64*49
#define NIP 6272    // 2*ED=6200 -> 49*128
#define NXP 256     // 129 -> 2*128
#define NOP 1664    // 1550 -> 13*128
#define NDT 3200    // ED -> 25*128
#define KDT 128     // DTR -> 128
#define DBC_LD 256

// prep job sizes (quads of 4 elems unless noted)
#define QIP 2508800   // NIP*KD/4
#define QXP 200704    // NXP*KE/4
#define QDT 102400    // NDT*KDT/4
#define QOP 1304576   // NOP*KE/4
#define AEL 49600     // NSTATE*ED scalars
#define QLM 51200     // VOCAB*KD/4
#define TEL 32768     // VOCAB*256 scalars (emb transpose)
#define PREP_N1 4166080   // QIP+QXP+QDT+QOP+AEL
#define PREP_N0 4250306   // PREP_N1+QLM+TEL+256+2

static inline int cdiv_h(int a, int b){ return (a + b - 1) / b; }

__device__ __forceinline__ float silu_f(float x){ return x / (1.0f + expf(-x)); }

using bf16x8 = __attribute__((ext_vector_type(8))) short;
using f32x4  = __attribute__((ext_vector_type(4))) float;

__device__ __forceinline__ void gload16(const void* g, void* l){
  __builtin_amdgcn_global_load_lds(
      (const __attribute__((address_space(1))) unsigned int*)g,
      (__attribute__((address_space(3))) unsigned int*)l,
      16, 0, 0);
}

// ---------------- permute: x (B,S,F,C,E) -> h (B*S, C*F*E) with d=(c*F+f)*E+e
__global__ void k_permute(const float* __restrict__ x, float* __restrict__ h){
  int idx = blockIdx.x * 256 + threadIdx.x;
  if (idx >= NBS * D_MODEL) return;
  int d = idx % D_MODEL;
  int row = idx / D_MODEL;
  int e = d % 5;
  int f = (d / 5) % 5;
  int c = d / 25;
  h[idx] = x[(((size_t)row * 5 + f) * 62 + c) * 5 + e];
}

// ---------------- cast+pad quad helper
__device__ __forceinline__ void cast4(const float* __restrict__ src,
                                      __hip_bfloat16* __restrict__ dst,
                                      int q, int N, int K, int Kp){
  int i4 = q * 4;
  int row = i4 / Kp;
  int col = i4 % Kp;
  const float* srow = src + (size_t)row * K;
  #pragma unroll
  for (int j = 0; j < 4; j++){
    int c = col + j;
    float v = (row < N && c < K) ? srow[c] : 0.f;
    dst[i4 + j] = __float2bfloat16(v);
  }
}

// ---------------- one-shot per-layer prep: weight casts + A_t (+ layer0 extras)
__global__ __launch_bounds__(256)
void k_prep(const float* __restrict__ ipw, const float* __restrict__ xpw,
            const float* __restrict__ dtw, const float* __restrict__ opw,
            const float* __restrict__ alog,
            const float* __restrict__ lmw, const float* __restrict__ embw,
            __hip_bfloat16* __restrict__ ipb, __hip_bfloat16* __restrict__ xpb,
            __hip_bfloat16* __restrict__ dtwb, __hip_bfloat16* __restrict__ opb,
            float* __restrict__ A_t,
            __hip_bfloat16* __restrict__ lmb,
            float* __restrict__ emb_t, float* __restrict__ sumw,
            float* __restrict__ stats, int l0){
  int idx = blockIdx.x * 256 + threadIdx.x;
  if (idx < QIP){ cast4(ipw, ipb, idx, 2 * ED, D_MODEL, KD); return; } idx -= QIP;
  if (idx < QXP){ cast4(xpw, xpb, idx, DBC_R, ED, KE); return; } idx -= QXP;
  if (idx < QDT){ cast4(dtw, dtwb, idx, ED, DTR, KDT); return; } idx -= QDT;
  if (idx < QOP){ cast4(opw, opb, idx, D_MODEL, ED, KE); return; } idx -= QOP;
  if (idx < AEL){
    int n = idx / ED, ch = idx % ED;
    A_t[idx] = -expf(alog[(size_t)ch * NSTATE + n]);
    return;
  } idx -= AEL;
  if (!l0) return;
  if (idx < QLM){ cast4(lmw, lmb, idx, VOCAB, D_MODEL, KD); return; } idx -= QLM;
  if (idx < TEL){
    int v = idx >> 8, o = idx & 255;
    emb_t[idx] = embw[(size_t)o * VOCAB + v];
    return;
  } idx -= TEL;
  if (idx < 256){
    const float* r = embw + (size_t)idx * VOCAB;
    float s = 0.f;
    for (int v = 0; v < VOCAB; v++) s += r[v];
    sumw[idx] = s;
    return;
  } idx -= 256;
  if (idx < 2) stats[idx] = 0.f;
}

// ---------------- rmsnorm -> bf16 padded row
__global__ void k_rmsnorm_bf16(const float* __restrict__ in, const float* __restrict__ w,
                               __hip_bfloat16* __restrict__ out, int D, int Kp){
  int row = blockIdx.x;
  const float* xr = in + (size_t)row * D;
  float ss = 0.f;
  for (int i = threadIdx.x; i < D; i += blockDim.x){ float v = xr[i]; ss = fmaf(v, v, ss); }
  __shared__ float red[4];
  __shared__ float sscale;
  int lane = threadIdx.x & 63, wv = threadIdx.x >> 6;
  #pragma unroll
  for (int o = 32; o > 0; o >>= 1) ss += __shfl_down(ss, o, 64);
  if (lane == 0) red[wv] = ss;
  __syncthreads();
  if (threadIdx.x == 0){
    float t = red[0] + red[1] + red[2] + red[3];
    sscale = 1.0f / sqrtf(t / (float)D + EPSV);
  }
  __syncthreads();
  float sc = sscale;
  __hip_bfloat16* orow = out + (size_t)row * Kp;
  for (int i = threadIdx.x; i < Kp; i += blockDim.x){
    float v = (i < D) ? xr[i] * sc * w[i] : 0.f;
    orow[i] = __float2bfloat16(v);
  }
}

// ---------------- 2-phase double-buffered bf16 MFMA NT GEMM
// + XCD-chunked swizzle + LDS chunk-XOR bank swizzle (source-permuted, rule #21)
// C[M,Nld] (+)= A[M,Kp] * B[Npad,Kp]^T over K chunk blockIdx.z.
// MODE via flags: PARTIAL -> write split-z partial buffer; ATOMIC -> atomicAdd;
// OUT_BF16 -> bf16 store; else fp32 store.
template<int SPLITS, bool ATOMIC, bool OUT_BF16, bool PARTIAL>
__global__ __launch_bounds__(256)
void k_gemm2(const __hip_bfloat16* __restrict__ A, const __hip_bfloat16* __restrict__ B,
             void* Cv, int Kp, int Nld, int Nreal){
  __shared__ short Al[2][4096];   // [buf][128 rows x 32 k]
  __shared__ short Bl[2][4096];
  // XCD-aware bijective swizzle (m204), column-major decode.
  const int gx = gridDim.x, gy = gridDim.y;
  const int nwg = gx * gy;
  const int wg = blockIdx.y * gx + blockIdx.x;
  const int q = nwg >> 3, r = nwg & 7;
  const int xcd = wg & 7, off = wg >> 3;
  const int nid = (xcd < r ? xcd * (q + 1) : r * (q + 1) + (xcd - r) * q) + off;
  const int bm = (nid % gy) * 128;
  const int bn = (nid / gy) * 128;

  const int t = threadIdx.x;
  const int tt8 = t * 8;

  int kb = 0, ke = Kp;
  if (SPLITS > 1){
    int Kc = ((Kp / SPLITS + 31) / 32) * 32;
    kb = blockIdx.z * Kc;
    ke = min(kb + Kc, Kp);
    if (kb >= ke) return;
  }
  const int nt = (ke - kb) / 32;

  // LDS bank swizzle: logical k-chunk kc stored at physical chunk kc^(row&3).
  // Writer thread t owns physical slot (row=t>>2, c=t&3) -> loads global
  // chunk (t&3)^((t>>2)&3). Reader applies the same XOR.
  const int cg = ((t & 3) ^ ((t >> 2) & 3)) * 8;
  const short* Ab = (const short*)A;
  const short* Bb = (const short*)B;
  const short* ga0 = Ab + (size_t)(bm + (t >> 2)) * Kp + cg;
  const short* ga1 = Ab + (size_t)(bm + 64 + (t >> 2)) * Kp + cg;
  const short* gb0 = Bb + (size_t)(bn + (t >> 2)) * Kp + cg;
  const short* gb1 = Bb + (size_t)(bn + 64 + (t >> 2)) * Kp + cg;

  const int l = t & 63;
  const int wid = t >> 6;
  const int wr = wid >> 1, wc = wid & 1;
  const int fr = l & 15;
  const int cc = ((l >> 4) ^ (l & 3)) * 8;   // physical chunk for this lane's fragment rows

  f32x4 acc[4][4] = {};

#define STAGE(buf, kof) do{ \
    gload16(ga0 + (kof), &Al[buf][tt8]); \
    gload16(ga1 + (kof), &Al[buf][2048 + tt8]); \
    gload16(gb0 + (kof), &Bl[buf][tt8]); \
    gload16(gb1 + (kof), &Bl[buf][2048 + tt8]); }while(0)

  STAGE(0, kb);
  __syncthreads();
  int cur = 0;
  for (int it = 0; it < nt; ++it){
    if (it + 1 < nt) STAGE(cur ^ 1, kb + (it + 1) * 32);
    bf16x8 af[4], bfr[4];
    #pragma unroll
    for (int m = 0; m < 4; m++)
      af[m] = *(const bf16x8*)&Al[cur][(wr * 64 + m * 16 + fr) * 32 + cc];
    #pragma unroll
    for (int n = 0; n < 4; n++)
      bfr[n] = *(const bf16x8*)&Bl[cur][(wc * 64 + n * 16 + fr) * 32 + cc];
    #pragma unroll
    for (int m = 0; m < 4; m++)
      #pragma unroll
      for (int n = 0; n < 4; n++)
        acc[m][n] = __builtin_amdgcn_mfma_f32_16x16x32_bf16(af[m], bfr[n], acc[m][n], 0, 0, 0);
    if (it + 1 < nt){ __syncthreads(); cur ^= 1; }
  }
#undef STAGE

  float* Cf = (float*)Cv;
  __hip_bfloat16* Cb = (__hip_bfloat16*)Cv;
  const size_t pstride = (size_t)gy * 128 * Nld;
  if (PARTIAL) Cf += (size_t)blockIdx.z * pstride;
  const int r0 = (l >> 4) * 4;
  #pragma unroll
  for (int m = 0; m < 4; m++){
    #pragma unroll
    for (int n = 0; n < 4; n++){
      int col = bn + wc * 64 + n * 16 + fr;
      if (col < Nreal){
        size_t base = (size_t)(bm + wr * 64 + m * 16 + r0) * Nld + col;
        #pragma unroll
        for (int j = 0; j < 4; j++){
          float v = acc[m][n][j];
          size_t o = base + (size_t)j * Nld;
          if (OUT_BF16)      Cb[o] = __float2bfloat16(v);
          else if (ATOMIC)   atomicAdd(&Cf[o], v);
          else               Cf[o] = v;
        }
      }
    }
  }
}

// ---------------- causal depthwise conv (S=3, k=4) + silu (xz bf16, stride NIP)
__global__ void k_conv_silu(const __hip_bfloat16* __restrict__ xz, const float* __restrict__ cw,
                            const float* __restrict__ cb, __hip_bfloat16* __restrict__ xc_b){
  int idx = blockIdx.x * 256 + threadIdx.x;
  if (idx >= B_SZ * KE) return;
  int ch = idx % KE;
  int b  = idx / KE;
  size_t ob = (size_t)b * SEQ * KE + ch;
  if (ch >= ED){
    __hip_bfloat16 z = __float2bfloat16(0.f);
    xc_b[ob] = z; xc_b[ob + KE] = z; xc_b[ob + 2 * KE] = z;
    return;
  }
  const __hip_bfloat16* base = xz + (size_t)b * SEQ * NIP + ch;
  float x0 = __bfloat162float(base[0]);
  float x1 = __bfloat162float(base[NIP]);
  float x2 = __bfloat162float(base[2 * NIP]);
  const float* w = cw + (size_t)ch * 4;
  float w1 = w[1], w2 = w[2], w3 = w[3];
  float bb = cb[ch];
  float s0 = silu_f(fmaf(w3, x0, bb));
  float s1 = silu_f(fmaf(w2, x0, fmaf(w3, x1, bb)));
  float s2 = silu_f(fmaf(w1, x0, fmaf(w2, x1, fmaf(w3, x2, bb))));
  xc_b[ob]          = __float2bfloat16(s0);
  xc_b[ob + KE]     = __float2bfloat16(s1);
  xc_b[ob + 2 * KE] = __float2bfloat16(s2);
}

// ---------------- x_proj split-K reduce: part[8][NBS][256] -> dbc fp32 + dbc_b bf16
__global__ __launch_bounds__(256)
void k_xred(const float* __restrict__ part, float* __restrict__ dbc,
            __hip_bfloat16* __restrict__ dbc_b){
  int idx = blockIdx.x * 256 + threadIdx.x;
  if (idx >= NBS * DBC_LD) return;
  float s = 0.f;
  #pragma unroll
  for (int p = 0; p < 8; p++) s += part[(size_t)p * NBS * DBC_LD + idx];
  dbc[idx] = s;
  int c = idx & 255, row = idx >> 8;
  if (c < KDT) dbc_b[(size_t)row * KDT + c] = __float2bfloat16(c < DTR ? s : 0.f);
}

// ---------------- lean scan: softplus(delta_b+bias) + SSM + D skip + z gate, in-place on xc_b
__global__ __launch_bounds__(256)
void k_scan2(const __hip_bfloat16* __restrict__ delta_b, const float* __restrict__ dbc,
             const float* __restrict__ dtb, const float* __restrict__ A_t,
             const float* __restrict__ Dp, const __hip_bfloat16* __restrict__ xz,
             __hip_bfloat16* __restrict__ xc_b){
  __shared__ float sB[SEQ][NSTATE], sC[SEQ][NSTATE];
  int b = blockIdx.y;
  if (threadIdx.x < SEQ * 2 * NSTATE){
    int t = threadIdx.x / (2 * NSTATE), r = threadIdx.x % (2 * NSTATE);
    float v = dbc[(size_t)(b * SEQ + t) * DBC_LD + DTR + r];
    if (r < NSTATE) sB[t][r] = v; else sC[t][r - NSTATE] = v;
  }
  __syncthreads();
  int ch = blockIdx.x * 256 + threadIdx.x;
  if (ch >= ED) return;

  float bias = dtb[ch];
  float dlt[SEQ];
  #pragma unroll
  for (int t = 0; t < SEQ; t++){
    float acc = __bfloat162float(delta_b[(size_t)(b * SEQ + t) * NDT + ch]) + bias;
    dlt[t] = (acc > 20.f) ? acc : log1pf(expf(acc));
  }

  size_t ob = (size_t)b * SEQ * KE + ch;
  float xcv[SEQ] = { __bfloat162float(xc_b[ob]),
                     __bfloat162float(xc_b[ob + KE]),
                     __bfloat162float(xc_b[ob + 2 * KE]) };
  float y[SEQ] = {0.f, 0.f, 0.f};
  #pragma unroll
  for (int n = 0; n < NSTATE; n++){
    float Av = A_t[(size_t)n * ED + ch];
    float hs = 0.f;
    #pragma unroll
    for (int t = 0; t < SEQ; t++){
      float dA = expf(dlt[t] * Av);
      hs = fmaf(dA, hs, dlt[t] * sB[t][n] * xcv[t]);
      y[t] = fmaf(hs, sC[t][n], y[t]);
    }
  }
  float dp = Dp[ch];
  const __hip_bfloat16* zbase = xz + (size_t)b * SEQ * NIP + ED + ch;
  #pragma unroll
  for (int t = 0; t < SEQ; t++){
    float z = __bfloat162float(zbase[(size_t)t * NIP]);
    float yy = fmaf(dp, xcv[t], y[t]);
    xc_b[ob + (size_t)t * KE] = __float2bfloat16(yy * silu_f(z));
  }
}

// ---------------- lm partial reduce -> logits, + stats (raw sum, sumsq) via atomics
__global__ __launch_bounds__(256)
void k_statsred(const float* __restrict__ part, float* __restrict__ logits,
                float* __restrict__ stats){
  float s = 0.f, ss = 0.f;
  for (int i = blockIdx.x * 256 + threadIdx.x; i < NBS * VOCAB; i += gridDim.x * 256){
    float v = 0.f;
    #pragma unroll
    for (int p = 0; p < 4; p++) v += part[(size_t)p * NBS * VOCAB + i];
    logits[i] = v;
    s += v; ss = fmaf(v, v, ss);
  }
  #pragma unroll
  for (int o = 32; o > 0; o >>= 1){ s += __shfl_down(s, o, 64); ss += __shfl_down(ss, o, 64); }
  __shared__ float rs[4], rss[4];
  int lane = threadIdx.x & 63, wv = threadIdx.x >> 6;
  if (lane == 0){ rs[wv] = s; rss[wv] = ss; }
  __syncthreads();
  if (threadIdx.x == 0){
    atomicAdd(&stats[0], rs[0] + rs[1] + rs[2] + rs[3]);
    atomicAdd(&stats[1], rss[0] + rss[1] + rss[2] + rss[3]);
  }
}

// ---------------- fused: proj = logits @ emb^T, BN normalize, write out[b,f,s,o]
__global__ __launch_bounds__(256)
void k_projfinal(const float* __restrict__ logits, const float* __restrict__ emb_t,
                 const float* __restrict__ sumw, const float* __restrict__ stats,
                 const float* __restrict__ bnw, const float* __restrict__ bnb,
                 const float* __restrict__ embb, float* __restrict__ out){
  __shared__ float row[VOCAB];
  int r = blockIdx.x;            // b*SEQ + s
  int o = threadIdx.x;           // 0..255
  if (o < VOCAB) row[o] = logits[(size_t)r * VOCAB + o];
  __syncthreads();
  float p = 0.f;
  #pragma unroll 8
  for (int v = 0; v < VOCAB; v++) p = fmaf(row[v], emb_t[v * 256 + o], p);
  const float invN = 1.0f / (float)(NBS * VOCAB);
  float mean = stats[0] * invN;
  float var  = stats[1] * invN - mean * mean;
  float rstd = rsqrtf(var + EPSV);
  int b = r / SEQ, s = r % SEQ;
  float sw = sumw[o];
  float base = rstd * (p - mean * sw);
  float eb = embb[o];
  #pragma unroll
  for (int f = 0; f < 5; f++){
    out[(((size_t)(b * 5 + f)) * SEQ + s) * 256 + o] = bnw[f] * base + bnb[f] * sw + eb;
  }
}

extern "C" void kernel_launch(void* const* d_in, const int* in_sizes, int n_in,
                              void* d_out, int out_size, void* d_ws, size_t ws_size,
                              hipStream_t stream) {
  const float* x          = (const float*)d_in[0];
  const float* in_proj_w  = (const float*)d_in[1];
  const float* conv_w     = (const float*)d_in[2];
  const float* conv_b     = (const float*)d_in[3];
  const float* x_proj_w   = (const float*)d_in[4];
  const float* dt_proj_w  = (const float*)d_in[5];
  const float* dt_proj_b  = (const float*)d_in[6];
  const float* A_log      = (const float*)d_in[7];
  const float* D_param    = (const float*)d_in[8];
  const float* out_proj_w = (const float*)d_in[9];
  const float* norm_w     = (const float*)d_in[10];
  const float* normf_w    = (const float*)d_in[11];
  const float* lm_head_w  = (const float*)d_in[12];
  const float* bn_w       = (const float*)d_in[13];
  const float* bn_b       = (const float*)d_in[14];
  const float* emb_w      = (const float*)d_in[15];
  const float* emb_b      = (const float*)d_in[16];

  float* ws = (float*)d_ws;
  float* h      = ws;                                   // NBS*D_MODEL
  float* dbc    = h      + (size_t)NBS * D_MODEL;       // NBS*DBC_LD
  float* logits = dbc    + (size_t)NBS * DBC_LD;        // NBS*VOCAB
  float* sumw   = logits + (size_t)NBS * VOCAB;         // 256
  float* stats  = sumw   + 256;                         // 2
  float* A_t    = stats  + 2;                           // NSTATE*ED
  float* emb_t  = A_t    + (size_t)NSTATE * ED;         // VOCAB*256
  float* xpart  = emb_t  + (size_t)VOCAB * 256;         // 8*NBS*DBC_LD
  float* lmpart = xpart  + (size_t)8 * NBS * DBC_LD;    // 4*NBS*VOCAB
  __hip_bfloat16* xz_b   = (__hip_bfloat16*)(lmpart + (size_t)4 * NBS * VOCAB); // NBS*NIP
  __hip_bfloat16* hn_b   = xz_b   + (size_t)NBS * NIP;  // NBS*KD
  __hip_bfloat16* xc_b   = hn_b   + (size_t)NBS * KD;   // NBS*KE
  __hip_bfloat16* dbc_b  = xc_b   + (size_t)NBS * KE;   // NBS*KDT
  __hip_bfloat16* dlt_b  = dbc_b  + (size_t)NBS * KDT;  // NBS*NDT
  __hip_bfloat16* ipb    = dlt_b  + (size_t)NBS * NDT;  // NIP*KD
  __hip_bfloat16* xpb    = ipb    + (size_t)NIP * KD;   // NXP*KE
  __hip_bfloat16* dtwb   = xpb    + (size_t)NXP * KE;   // NDT*KDT
  __hip_bfloat16* opb    = dtwb   + (size_t)NDT * KDT;  // NOP*KE
  __hip_bfloat16* lmb    = opb    + (size_t)NOP * KE;   // VOCAB*KD
  size_t need = (size_t)((char*)(lmb + (size_t)VOCAB * KD) - (char*)ws);
  if (ws_size < need) return;

  k_permute<<<cdiv_h(NBS * D_MODEL, 256), 256, 0, stream>>>(x, h);

  for (int l = 0; l < 2; l++){
    const float* ipw = in_proj_w  + (size_t)l * 2 * ED * D_MODEL;
    const float* cw  = conv_w     + (size_t)l * ED * 4;
    const float* cb  = conv_b     + (size_t)l * ED;
    const float* xpw = x_proj_w   + (size_t)l * DBC_R * ED;
    const float* dtw = dt_proj_w  + (size_t)l * ED * DTR;
    const float* dtb = dt_proj_b  + (size_t)l * ED;
    const float* al  = A_log      + (size_t)l * ED * NSTATE;
    const float* dp  = D_param    + (size_t)l * ED;
    const float* opw = out_proj_w + (size_t)l * D_MODEL * ED;
    const float* nw  = norm_w     + (size_t)l * D_MODEL;

    // per-layer prep: weight casts + A_t (+ layer0: lm cast, emb_t, sumw, stats zero)
    k_prep<<<cdiv_h(l == 0 ? PREP_N0 : PREP_N1, 256), 256, 0, stream>>>(
        ipw, xpw, dtw, opw, al, lm_head_w, emb_w,
        ipb, xpb, dtwb, opb, A_t, lmb, emb_t, sumw, stats, l == 0 ? 1 : 0);

    k_rmsnorm_bf16<<<NBS, 256, 0, stream>>>(h, nw, hn_b, D_MODEL, KD);

    // in_proj: xz_b[1536,6272](bf16) = hn_b @ ipb^T
    k_gemm2<1, false, true, false><<<dim3(NIP / 128, NBS / 128, 1), 256, 0, stream>>>(
        hn_b, ipb, xz_b, KD, NIP, NIP);

    k_conv_silu<<<cdiv_h(B_SZ * KE, 256), 256, 0, stream>>>(xz_b, cw, cb, xc_b);

    // x_proj (split-K 8, partials): xpart[z] = xc_b @ xpb^T chunks
    k_gemm2<8, false, false, true><<<dim3(NXP / 128, NBS / 128, 8), 256, 0, stream>>>(
        xc_b, xpb, xpart, KE, DBC_LD, DBC_LD);
    k_xred<<<cdiv_h(NBS * DBC_LD, 256), 256, 0, stream>>>(xpart, dbc, dbc_b);

    // dt_proj: dlt_b[1536,3200](bf16) = dbc_b[1536,128] @ dtwb^T
    k_gemm2<1, false, true, false><<<dim3(NDT / 128, NBS / 128, 1), 256, 0, stream>>>(
        dbc_b, dtwb, dlt_b, KDT, NDT, NDT);

    k_scan2<<<dim3(cdiv_h(ED, 256), B_SZ), 256, 0, stream>>>(
        dlt_b, dbc, dtb, A_t, dp, xz_b, xc_b);

    // out_proj (split-K 4, atomic, residual in place): h += xc_b @ opb^T
    k_gemm2<4, true, false, false><<<dim3(NOP / 128, NBS / 128, 4), 256, 0, stream>>>(
        xc_b, opb, h, KE, D_MODEL, D_MODEL);
  }

  // final norm + lm head (split-K 4, partials) + fused reduce/stats
  k_rmsnorm_bf16<<<NBS, 256, 0, stream>>>(h, normf_w, hn_b, D_MODEL, KD);
  k_gemm2<4, false, false, true><<<dim3(1, NBS / 128, 4), 256, 0, stream>>>(
      hn_b, lmb, lmpart, KD, VOCAB, VOCAB);
  k_statsred<<<192, 256, 0, stream>>>(lmpart, logits, stats);

  k_projfinal<<<NBS, 256, 0, stream>>>(logits, emb_t, sumw, stats,
                                       bn_w, bn_b, emb_b, (float*)d_out);
}

// Round 7
// 497.814 us; speedup vs baseline: 1.1456x; 1.1456x over previous
//
#include <hip/hip_runtime.h>
#include <hip/hip_bf16.h>
#include <math.h>

#define B_SZ 512
#define SEQ 3
#define D_MODEL 1550
#define ED 3100
#define NSTATE 16
#define DTR 97
#define DBC_R 129   // DTR + 2*NSTATE
#define VOCAB 128
#define NBS (B_SZ*SEQ)       // 1536
#define EPSV 1e-5f

// padded dims
#define KD 1600     // D_MODEL -> 64*25
#define KE 3136     // ED -> 64*49
#define NIP 6272    // 2*ED=6200 -> 49*128
#define NXP 256     // 129 -> 2*128
#define NOP 1664    // 1550 -> 13*128
#define NDT 3200    // ED -> 25*128
#define KDT 128     // DTR -> 128
#define DBC_LD 256

// prep job sizes (quads of 4 elems unless noted)
#define QIP 2508800   // NIP*KD/4
#define QXP 200704    // NXP*KE/4
#define QDT 102400    // NDT*KDT/4
#define QOP 1304576   // NOP*KE/4
#define AEL 49600     // NSTATE*ED scalars
#define QLM 51200     // VOCAB*KD/4
#define TEL 32768     // VOCAB*256 scalars (emb transpose)
#define PREP_N1 4166080   // QIP+QXP+QDT+QOP+AEL
#define PREP_N0 4250306   // PREP_N1+QLM+TEL+256+2

static inline int cdiv_h(int a, int b){ return (a + b - 1) / b; }

__device__ __forceinline__ float silu_f(float x){ return x / (1.0f + expf(-x)); }

using bf16x8 = __attribute__((ext_vector_type(8))) short;
using f32x4  = __attribute__((ext_vector_type(4))) float;

__device__ __forceinline__ void gload16(const void* g, void* l){
  __builtin_amdgcn_global_load_lds(
      (const __attribute__((address_space(1))) unsigned int*)g,
      (__attribute__((address_space(3))) unsigned int*)l,
      16, 0, 0);
}

__device__ __forceinline__ unsigned short bfbits(float v){
  __hip_bfloat16 b = __float2bfloat16(v);
  return *(unsigned short*)&b;
}

// ---------------- permute: x (B,S,F,C,E) -> h (B*S, C*F*E) with d=(c*F+f)*E+e
__global__ void k_permute(const float* __restrict__ x, float* __restrict__ h){
  int idx = blockIdx.x * 256 + threadIdx.x;
  if (idx >= NBS * D_MODEL) return;
  int d = idx % D_MODEL;
  int row = idx / D_MODEL;
  int e = d % 5;
  int f = (d / 5) % 5;
  int c = d / 25;
  h[idx] = x[(((size_t)row * 5 + f) * 62 + c) * 5 + e];
}

// ---------------- cast+pad quad helper (vectorized 8B store)
__device__ __forceinline__ void cast4(const float* __restrict__ src,
                                      __hip_bfloat16* __restrict__ dst,
                                      int q, int N, int K, int Kp){
  int i4 = q * 4;
  int row = i4 / Kp;
  int col = i4 % Kp;
  const float* srow = src + (size_t)row * K;
  ushort4 o;
  o.x = bfbits((row < N && col + 0 < K) ? srow[col + 0] : 0.f);
  o.y = bfbits((row < N && col + 1 < K) ? srow[col + 1] : 0.f);
  o.z = bfbits((row < N && col + 2 < K) ? srow[col + 2] : 0.f);
  o.w = bfbits((row < N && col + 3 < K) ? srow[col + 3] : 0.f);
  *(ushort4*)(dst + i4) = o;
}

// ---------------- one-shot per-layer prep: weight casts + A_t (+ layer0 extras)
__global__ __launch_bounds__(256)
void k_prep(const float* __restrict__ ipw, const float* __restrict__ xpw,
            const float* __restrict__ dtw, const float* __restrict__ opw,
            const float* __restrict__ alog,
            const float* __restrict__ lmw, const float* __restrict__ embw,
            __hip_bfloat16* __restrict__ ipb, __hip_bfloat16* __restrict__ xpb,
            __hip_bfloat16* __restrict__ dtwb, __hip_bfloat16* __restrict__ opb,
            float* __restrict__ A_t,
            __hip_bfloat16* __restrict__ lmb,
            float* __restrict__ emb_t, float* __restrict__ sumw,
            float* __restrict__ stats, int l0){
  int idx = blockIdx.x * 256 + threadIdx.x;
  if (idx < QIP){ cast4(ipw, ipb, idx, 2 * ED, D_MODEL, KD); return; } idx -= QIP;
  if (idx < QXP){ cast4(xpw, xpb, idx, DBC_R, ED, KE); return; } idx -= QXP;
  if (idx < QDT){ cast4(dtw, dtwb, idx, ED, DTR, KDT); return; } idx -= QDT;
  if (idx < QOP){ cast4(opw, opb, idx, D_MODEL, ED, KE); return; } idx -= QOP;
  if (idx < AEL){
    int n = idx / ED, ch = idx % ED;
    A_t[idx] = -expf(alog[(size_t)ch * NSTATE + n]);
    return;
  } idx -= AEL;
  if (!l0) return;
  if (idx < QLM){ cast4(lmw, lmb, idx, VOCAB, D_MODEL, KD); return; } idx -= QLM;
  if (idx < TEL){
    int v = idx >> 8, o = idx & 255;
    emb_t[idx] = embw[(size_t)o * VOCAB + v];
    return;
  } idx -= TEL;
  if (idx < 256){
    const float* r = embw + (size_t)idx * VOCAB;
    float s = 0.f;
    for (int v = 0; v < VOCAB; v++) s += r[v];
    sumw[idx] = s;
    return;
  } idx -= 256;
  if (idx < 2) stats[idx] = 0.f;
}

// ---------------- rmsnorm -> bf16 padded row
__global__ void k_rmsnorm_bf16(const float* __restrict__ in, const float* __restrict__ w,
                               __hip_bfloat16* __restrict__ out, int D, int Kp){
  int row = blockIdx.x;
  const float* xr = in + (size_t)row * D;
  float ss = 0.f;
  for (int i = threadIdx.x; i < D; i += blockDim.x){ float v = xr[i]; ss = fmaf(v, v, ss); }
  __shared__ float red[4];
  __shared__ float sscale;
  int lane = threadIdx.x & 63, wv = threadIdx.x >> 6;
  #pragma unroll
  for (int o = 32; o > 0; o >>= 1) ss += __shfl_down(ss, o, 64);
  if (lane == 0) red[wv] = ss;
  __syncthreads();
  if (threadIdx.x == 0){
    float t = red[0] + red[1] + red[2] + red[3];
    sscale = 1.0f / sqrtf(t / (float)D + EPSV);
  }
  __syncthreads();
  float sc = sscale;
  __hip_bfloat16* orow = out + (size_t)row * Kp;
  for (int i = threadIdx.x; i < Kp; i += blockDim.x){
    float v = (i < D) ? xr[i] * sc * w[i] : 0.f;
    orow[i] = __float2bfloat16(v);
  }
}

// ---------------- 2-phase double-buffered bf16 MFMA NT GEMM
// + XCD-chunked swizzle + LDS chunk-XOR bank swizzle (source-permuted, rule #21)
// C[M,Nld] = A[M,Kp] * B[Npad,Kp]^T over K chunk blockIdx.z.
// PARTIAL -> offset output by blockIdx.z * (gy*128*Nld). OUT_BF16 -> bf16 stores.
template<int SPLITS, bool OUT_BF16, bool PARTIAL>
__global__ __launch_bounds__(256)
void k_gemm2(const __hip_bfloat16* __restrict__ A, const __hip_bfloat16* __restrict__ B,
             void* Cv, int Kp, int Nld, int Nreal){
  __shared__ short Al[2][4096];   // [buf][128 rows x 32 k]
  __shared__ short Bl[2][4096];
  // XCD-aware bijective swizzle (m204), column-major decode.
  const int gx = gridDim.x, gy = gridDim.y;
  const int nwg = gx * gy;
  const int wg = blockIdx.y * gx + blockIdx.x;
  const int q = nwg >> 3, r = nwg & 7;
  const int xcd = wg & 7, off = wg >> 3;
  const int nid = (xcd < r ? xcd * (q + 1) : r * (q + 1) + (xcd - r) * q) + off;
  const int bm = (nid % gy) * 128;
  const int bn = (nid / gy) * 128;

  const int t = threadIdx.x;
  const int tt8 = t * 8;

  int kb = 0, ke = Kp;
  if (SPLITS > 1){
    int Kc = ((Kp / SPLITS + 31) / 32) * 32;
    kb = blockIdx.z * Kc;
    ke = min(kb + Kc, Kp);
    if (kb >= ke) return;
  }
  const int nt = (ke - kb) / 32;

  // LDS bank swizzle: logical k-chunk kc stored at physical chunk kc^(row&3).
  const int cg = ((t & 3) ^ ((t >> 2) & 3)) * 8;
  const short* Ab = (const short*)A;
  const short* Bb = (const short*)B;
  const short* ga0 = Ab + (size_t)(bm + (t >> 2)) * Kp + cg;
  const short* ga1 = Ab + (size_t)(bm + 64 + (t >> 2)) * Kp + cg;
  const short* gb0 = Bb + (size_t)(bn + (t >> 2)) * Kp + cg;
  const short* gb1 = Bb + (size_t)(bn + 64 + (t >> 2)) * Kp + cg;

  const int l = t & 63;
  const int wid = t >> 6;
  const int wr = wid >> 1, wc = wid & 1;
  const int fr = l & 15;
  const int cc = ((l >> 4) ^ (l & 3)) * 8;   // physical chunk for this lane's rows

  f32x4 acc[4][4] = {};

#define STAGE(buf, kof) do{ \
    gload16(ga0 + (kof), &Al[buf][tt8]); \
    gload16(ga1 + (kof), &Al[buf][2048 + tt8]); \
    gload16(gb0 + (kof), &Bl[buf][tt8]); \
    gload16(gb1 + (kof), &Bl[buf][2048 + tt8]); }while(0)

  STAGE(0, kb);
  __syncthreads();
  int cur = 0;
  for (int it = 0; it < nt; ++it){
    if (it + 1 < nt) STAGE(cur ^ 1, kb + (it + 1) * 32);
    bf16x8 af[4], bfr[4];
    #pragma unroll
    for (int m = 0; m < 4; m++)
      af[m] = *(const bf16x8*)&Al[cur][(wr * 64 + m * 16 + fr) * 32 + cc];
    #pragma unroll
    for (int n = 0; n < 4; n++)
      bfr[n] = *(const bf16x8*)&Bl[cur][(wc * 64 + n * 16 + fr) * 32 + cc];
    #pragma unroll
    for (int m = 0; m < 4; m++)
      #pragma unroll
      for (int n = 0; n < 4; n++)
        acc[m][n] = __builtin_amdgcn_mfma_f32_16x16x32_bf16(af[m], bfr[n], acc[m][n], 0, 0, 0);
    if (it + 1 < nt){ __syncthreads(); cur ^= 1; }
  }
#undef STAGE

  float* Cf = (float*)Cv;
  __hip_bfloat16* Cb = (__hip_bfloat16*)Cv;
  if (PARTIAL){
    const size_t pstride = (size_t)gy * 128 * Nld;
    if (OUT_BF16) Cb += (size_t)blockIdx.z * pstride;
    else          Cf += (size_t)blockIdx.z * pstride;
  }
  const int r0 = (l >> 4) * 4;
  #pragma unroll
  for (int m = 0; m < 4; m++){
    #pragma unroll
    for (int n = 0; n < 4; n++){
      int col = bn + wc * 64 + n * 16 + fr;
      if (col < Nreal){
        size_t base = (size_t)(bm + wr * 64 + m * 16 + r0) * Nld + col;
        #pragma unroll
        for (int j = 0; j < 4; j++){
          float v = acc[m][n][j];
          size_t o = base + (size_t)j * Nld;
          if (OUT_BF16) Cb[o] = __float2bfloat16(v);
          else          Cf[o] = v;
        }
      }
    }
  }
}

// ---------------- causal depthwise conv (S=3, k=4) + silu (xz bf16, stride NIP)
__global__ void k_conv_silu(const __hip_bfloat16* __restrict__ xz, const float* __restrict__ cw,
                            const float* __restrict__ cb, __hip_bfloat16* __restrict__ xc_b){
  int idx = blockIdx.x * 256 + threadIdx.x;
  if (idx >= B_SZ * KE) return;
  int ch = idx % KE;
  int b  = idx / KE;
  size_t ob = (size_t)b * SEQ * KE + ch;
  if (ch >= ED){
    __hip_bfloat16 z = __float2bfloat16(0.f);
    xc_b[ob] = z; xc_b[ob + KE] = z; xc_b[ob + 2 * KE] = z;
    return;
  }
  const __hip_bfloat16* base = xz + (size_t)b * SEQ * NIP + ch;
  float x0 = __bfloat162float(base[0]);
  float x1 = __bfloat162float(base[NIP]);
  float x2 = __bfloat162float(base[2 * NIP]);
  const float* w = cw + (size_t)ch * 4;
  float w1 = w[1], w2 = w[2], w3 = w[3];
  float bb = cb[ch];
  float s0 = silu_f(fmaf(w3, x0, bb));
  float s1 = silu_f(fmaf(w2, x0, fmaf(w3, x1, bb)));
  float s2 = silu_f(fmaf(w1, x0, fmaf(w2, x1, fmaf(w3, x2, bb))));
  xc_b[ob]          = __float2bfloat16(s0);
  xc_b[ob + KE]     = __float2bfloat16(s1);
  xc_b[ob + 2 * KE] = __float2bfloat16(s2);
}

// ---------------- x_proj split-K reduce: part[8][NBS][256] -> dbc fp32 + dbc_b bf16
__global__ __launch_bounds__(256)
void k_xred(const float* __restrict__ part, float* __restrict__ dbc,
            __hip_bfloat16* __restrict__ dbc_b){
  int idx = blockIdx.x * 256 + threadIdx.x;
  if (idx >= NBS * DBC_LD) return;
  float s = 0.f;
  #pragma unroll
  for (int p = 0; p < 8; p++) s += part[(size_t)p * NBS * DBC_LD + idx];
  dbc[idx] = s;
  int c = idx & 255, row = idx >> 8;
  if (c < KDT) dbc_b[(size_t)row * KDT + c] = __float2bfloat16(c < DTR ? s : 0.f);
}

// ---------------- out_proj split-K reduce (bf16 partials) + residual into h
__global__ __launch_bounds__(256)
void k_ored(const __hip_bfloat16* __restrict__ part, float* __restrict__ h){
  int idx = blockIdx.x * 256 + threadIdx.x;
  if (idx >= NBS * D_MODEL) return;
  float s = h[idx];
  #pragma unroll
  for (int p = 0; p < 4; p++)
    s += __bfloat162float(part[(size_t)p * NBS * D_MODEL + idx]);
  h[idx] = s;
}

// ---------------- lean scan: softplus(delta_b+bias) + SSM + D skip + z gate, in-place on xc_b
__global__ __launch_bounds__(256)
void k_scan2(const __hip_bfloat16* __restrict__ delta_b, const float* __restrict__ dbc,
             const float* __restrict__ dtb, const float* __restrict__ A_t,
             const float* __restrict__ Dp, const __hip_bfloat16* __restrict__ xz,
             __hip_bfloat16* __restrict__ xc_b){
  __shared__ float sB[SEQ][NSTATE], sC[SEQ][NSTATE];
  int b = blockIdx.y;
  if (threadIdx.x < SEQ * 2 * NSTATE){
    int t = threadIdx.x / (2 * NSTATE), r = threadIdx.x % (2 * NSTATE);
    float v = dbc[(size_t)(b * SEQ + t) * DBC_LD + DTR + r];
    if (r < NSTATE) sB[t][r] = v; else sC[t][r - NSTATE] = v;
  }
  __syncthreads();
  int ch = blockIdx.x * 256 + threadIdx.x;
  if (ch >= ED) return;

  float bias = dtb[ch];
  float dlt[SEQ];
  #pragma unroll
  for (int t = 0; t < SEQ; t++){
    float acc = __bfloat162float(delta_b[(size_t)(b * SEQ + t) * NDT + ch]) + bias;
    dlt[t] = (acc > 20.f) ? acc : log1pf(expf(acc));
  }

  size_t ob = (size_t)b * SEQ * KE + ch;
  float xcv[SEQ] = { __bfloat162float(xc_b[ob]),
                     __bfloat162float(xc_b[ob + KE]),
                     __bfloat162float(xc_b[ob + 2 * KE]) };
  float y[SEQ] = {0.f, 0.f, 0.f};
  #pragma unroll
  for (int n = 0; n < NSTATE; n++){
    float Av = A_t[(size_t)n * ED + ch];
    float hs = 0.f;
    #pragma unroll
    for (int t = 0; t < SEQ; t++){
      float dA = expf(dlt[t] * Av);
      hs = fmaf(dA, hs, dlt[t] * sB[t][n] * xcv[t]);
      y[t] = fmaf(hs, sC[t][n], y[t]);
    }
  }
  float dp = Dp[ch];
  const __hip_bfloat16* zbase = xz + (size_t)b * SEQ * NIP + ED + ch;
  #pragma unroll
  for (int t = 0; t < SEQ; t++){
    float z = __bfloat162float(zbase[(size_t)t * NIP]);
    float yy = fmaf(dp, xcv[t], y[t]);
    xc_b[ob + (size_t)t * KE] = __float2bfloat16(yy * silu_f(z));
  }
}

// ---------------- lm partial reduce -> logits, + stats (raw sum, sumsq) via atomics
__global__ __launch_bounds__(256)
void k_statsred(const float* __restrict__ part, float* __restrict__ logits,
                float* __restrict__ stats){
  float s = 0.f, ss = 0.f;
  for (int i = blockIdx.x * 256 + threadIdx.x; i < NBS * VOCAB; i += gridDim.x * 256){
    float v = 0.f;
    #pragma unroll
    for (int p = 0; p < 4; p++) v += part[(size_t)p * NBS * VOCAB + i];
    logits[i] = v;
    s += v; ss = fmaf(v, v, ss);
  }
  #pragma unroll
  for (int o = 32; o > 0; o >>= 1){ s += __shfl_down(s, o, 64); ss += __shfl_down(ss, o, 64); }
  __shared__ float rs[4], rss[4];
  int lane = threadIdx.x & 63, wv = threadIdx.x >> 6;
  if (lane == 0){ rs[wv] = s; rss[wv] = ss; }
  __syncthreads();
  if (threadIdx.x == 0){
    atomicAdd(&stats[0], rs[0] + rs[1] + rs[2] + rs[3]);
    atomicAdd(&stats[1], rss[0] + rss[1] + rss[2] + rss[3]);
  }
}

// ---------------- fused: proj = logits @ emb^T, BN normalize, write out[b,f,s,o]
__global__ __launch_bounds__(256)
void k_projfinal(const float* __restrict__ logits, const float* __restrict__ emb_t,
                 const float* __restrict__ sumw, const float* __restrict__ stats,
                 const float* __restrict__ bnw, const float* __restrict__ bnb,
                 const float* __restrict__ embb, float* __restrict__ out){
  __shared__ float row[VOCAB];
  int r = blockIdx.x;            // b*SEQ + s
  int o = threadIdx.x;           // 0..255
  if (o < VOCAB) row[o] = logits[(size_t)r * VOCAB + o];
  __syncthreads();
  float p = 0.f;
  #pragma unroll 8
  for (int v = 0; v < VOCAB; v++) p = fmaf(row[v], emb_t[v * 256 + o], p);
  const float invN = 1.0f / (float)(NBS * VOCAB);
  float mean = stats[0] * invN;
  float var  = stats[1] * invN - mean * mean;
  float rstd = rsqrtf(var + EPSV);
  int b = r / SEQ, s = r % SEQ;
  float sw = sumw[o];
  float base = rstd * (p - mean * sw);
  float eb = embb[o];
  #pragma unroll
  for (int f = 0; f < 5; f++){
    out[(((size_t)(b * 5 + f)) * SEQ + s) * 256 + o] = bnw[f] * base + bnb[f] * sw + eb;
  }
}

extern "C" void kernel_launch(void* const* d_in, const int* in_sizes, int n_in,
                              void* d_out, int out_size, void* d_ws, size_t ws_size,
                              hipStream_t stream) {
  const float* x          = (const float*)d_in[0];
  const float* in_proj_w  = (const float*)d_in[1];
  const float* conv_w     = (const float*)d_in[2];
  const float* conv_b     = (const float*)d_in[3];
  const float* x_proj_w   = (const float*)d_in[4];
  const float* dt_proj_w  = (const float*)d_in[5];
  const float* dt_proj_b  = (const float*)d_in[6];
  const float* A_log      = (const float*)d_in[7];
  const float* D_param    = (const float*)d_in[8];
  const float* out_proj_w = (const float*)d_in[9];
  const float* norm_w     = (const float*)d_in[10];
  const float* normf_w    = (const float*)d_in[11];
  const float* lm_head_w  = (const float*)d_in[12];
  const float* bn_w       = (const float*)d_in[13];
  const float* bn_b       = (const float*)d_in[14];
  const float* emb_w      = (const float*)d_in[15];
  const float* emb_b      = (const float*)d_in[16];

  float* ws = (float*)d_ws;
  float* h      = ws;                                   // NBS*D_MODEL
  float* dbc    = h      + (size_t)NBS * D_MODEL;       // NBS*DBC_LD
  float* logits = dbc    + (size_t)NBS * DBC_LD;        // NBS*VOCAB
  float* sumw   = logits + (size_t)NBS * VOCAB;         // 256
  float* stats  = sumw   + 256;                         // 2
  float* A_t    = stats  + 2;                           // NSTATE*ED
  float* emb_t  = A_t    + (size_t)NSTATE * ED;         // VOCAB*256
  // shared partial arena: xpart(8*NBS*256 f32 = 12.6MB) | opart(4*NBS*1550 bf16 = 19.0MB)
  // | lmpart(4*NBS*128 f32 = 3.1MB). Lifetimes disjoint (xred < out_proj < next x_proj; lm last).
  float* spart  = emb_t  + (size_t)VOCAB * 256;
  size_t spart_f = ((size_t)4 * NBS * D_MODEL * 2 + 3) / 4; // bytes of bf16 opart in floats
  float* xpart  = spart;
  float* lmpart = spart;
  __hip_bfloat16* opart = (__hip_bfloat16*)spart;
  __hip_bfloat16* xz_b   = (__hip_bfloat16*)(spart + spart_f); // NBS*NIP
  __hip_bfloat16* hn_b   = xz_b   + (size_t)NBS * NIP;  // NBS*KD
  __hip_bfloat16* xc_b   = hn_b   + (size_t)NBS * KD;   // NBS*KE
  __hip_bfloat16* dbc_b  = xc_b   + (size_t)NBS * KE;   // NBS*KDT
  __hip_bfloat16* dlt_b  = dbc_b  + (size_t)NBS * KDT;  // NBS*NDT
  __hip_bfloat16* ipb    = dlt_b  + (size_t)NBS * NDT;  // NIP*KD
  __hip_bfloat16* xpb    = ipb    + (size_t)NIP * KD;   // NXP*KE
  __hip_bfloat16* dtwb   = xpb    + (size_t)NXP * KE;   // NDT*KDT
  __hip_bfloat16* opb    = dtwb   + (size_t)NDT * KDT;  // NOP*KE
  __hip_bfloat16* lmb    = opb    + (size_t)NOP * KE;   // VOCAB*KD
  size_t need = (size_t)((char*)(lmb + (size_t)VOCAB * KD) - (char*)ws);
  if (ws_size < need) return;

  k_permute<<<cdiv_h(NBS * D_MODEL, 256), 256, 0, stream>>>(x, h);

  for (int l = 0; l < 2; l++){
    const float* ipw = in_proj_w  + (size_t)l * 2 * ED * D_MODEL;
    const float* cw  = conv_w     + (size_t)l * ED * 4;
    const float* cb  = conv_b     + (size_t)l * ED;
    const float* xpw = x_proj_w   + (size_t)l * DBC_R * ED;
    const float* dtw = dt_proj_w  + (size_t)l * ED * DTR;
    const float* dtb = dt_proj_b  + (size_t)l * ED;
    const float* al  = A_log      + (size_t)l * ED * NSTATE;
    const float* dp  = D_param    + (size_t)l * ED;
    const float* opw = out_proj_w + (size_t)l * D_MODEL * ED;
    const float* nw  = norm_w     + (size_t)l * D_MODEL;

    // per-layer prep: weight casts + A_t (+ layer0: lm cast, emb_t, sumw, stats zero)
    k_prep<<<cdiv_h(l == 0 ? PREP_N0 : PREP_N1, 256), 256, 0, stream>>>(
        ipw, xpw, dtw, opw, al, lm_head_w, emb_w,
        ipb, xpb, dtwb, opb, A_t, lmb, emb_t, sumw, stats, l == 0 ? 1 : 0);

    k_rmsnorm_bf16<<<NBS, 256, 0, stream>>>(h, nw, hn_b, D_MODEL, KD);

    // in_proj: xz_b[1536,6272](bf16) = hn_b @ ipb^T
    k_gemm2<1, true, false><<<dim3(NIP / 128, NBS / 128, 1), 256, 0, stream>>>(
        hn_b, ipb, xz_b, KD, NIP, NIP);

    k_conv_silu<<<cdiv_h(B_SZ * KE, 256), 256, 0, stream>>>(xz_b, cw, cb, xc_b);

    // x_proj (split-K 8, fp32 partials): xpart[z] = xc_b @ xpb^T chunks
    k_gemm2<8, false, true><<<dim3(NXP / 128, NBS / 128, 8), 256, 0, stream>>>(
        xc_b, xpb, xpart, KE, DBC_LD, DBC_LD);
    k_xred<<<cdiv_h(NBS * DBC_LD, 256), 256, 0, stream>>>(xpart, dbc, dbc_b);

    // dt_proj: dlt_b[1536,3200](bf16) = dbc_b[1536,128] @ dtwb^T
    k_gemm2<1, true, false><<<dim3(NDT / 128, NBS / 128, 1), 256, 0, stream>>>(
        dbc_b, dtwb, dlt_b, KDT, NDT, NDT);

    k_scan2<<<dim3(cdiv_h(ED, 256), B_SZ), 256, 0, stream>>>(
        dlt_b, dbc, dtb, A_t, dp, xz_b, xc_b);

    // out_proj (split-K 4, bf16 partials): opart[z] = xc_b @ opb^T chunks
    k_gemm2<4, true, true><<<dim3(NOP / 128, NBS / 128, 4), 256, 0, stream>>>(
        xc_b, opb, opart, KE, D_MODEL, D_MODEL);
    // reduce + residual into h
    k_ored<<<cdiv_h(NBS * D_MODEL, 256), 256, 0, stream>>>(opart, h);
  }

  // final norm + lm head (split-K 4, fp32 partials) + fused reduce/stats
  k_rmsnorm_bf16<<<NBS, 256, 0, stream>>>(h, normf_w, hn_b, D_MODEL, KD);
  k_gemm2<4, false, true><<<dim3(1, NBS / 128, 4), 256, 0, stream>>>(
      hn_b, lmb, lmpart, KD, VOCAB, VOCAB);
  k_statsred<<<192, 256, 0, stream>>>(lmpart, logits, stats);

  k_projfinal<<<NBS, 256, 0, stream>>>(logits, emb_t, sumw, stats,
                                       bn_w, bn_b, emb_b, (float*)d_out);
}

// Round 8
// 492.093 us; speedup vs baseline: 1.1589x; 1.0116x over previous
//
#include <hip/hip_runtime.h>
#include <hip/hip_bf16.h>
#include <math.h>

#define B_SZ 512
#define SEQ 3
#define D_MODEL 1550
#define ED 3100
#define NSTATE 16
#define DTR 97
#define DBC_R 129   // DTR + 2*NSTATE
#define VOCAB 128
#define NBS (B_SZ*SEQ)       // 1536
#define EPSV 1e-5f

// padded dims
#define KD 1600     // D_MODEL -> 64*25
#define KE 3136     // ED -> 64*49
#define NIP 6272    // 2*ED=6200 -> 49*128
#define NXP 256     // 129 -> 2*128
#define NOP 1664    // 1550 -> 13*128
#define NDT 3200    // ED -> 25*128
#define KDT 128     // DTR -> 128
#define DBC_LD 256

// prep job sizes (quads of 4 elems unless noted)
#define QIP 2508800   // NIP*KD/4
#define QXP 200704    // NXP*KE/4
#define QDT 102400    // NDT*KDT/4
#define QOP 1304576   // NOP*KE/4
#define AEL 49600     // NSTATE*ED scalars
#define QLM 51200     // VOCAB*KD/4
#define TEL 32768     // VOCAB*256 scalars (emb transpose)
#define PREP_N1 4166080   // QIP+QXP+QDT+QOP+AEL
#define PREP_N0 4250306   // PREP_N1+QLM+TEL+256+2

static inline int cdiv_h(int a, int b){ return (a + b - 1) / b; }

__device__ __forceinline__ float silu_f(float x){ return x / (1.0f + expf(-x)); }

using bf16x8 = __attribute__((ext_vector_type(8))) short;
using f32x4  = __attribute__((ext_vector_type(4))) float;

__device__ __forceinline__ void gload16(const void* g, void* l){
  __builtin_amdgcn_global_load_lds(
      (const __attribute__((address_space(1))) unsigned int*)g,
      (__attribute__((address_space(3))) unsigned int*)l,
      16, 0, 0);
}

__device__ __forceinline__ unsigned short bfbits(float v){
  __hip_bfloat16 b = __float2bfloat16(v);
  return *(unsigned short*)&b;
}

// ---------------- fused permute + layer0 rmsnorm
// x row (b,s) is 1550 contiguous floats in (f,c,e) order; dest d=(c*5+f)*5+e.
// sum-of-squares is permutation-invariant.
__global__ __launch_bounds__(256)
void k_perm_rms(const float* __restrict__ x, const float* __restrict__ w,
                float* __restrict__ h, __hip_bfloat16* __restrict__ hn){
  int row = blockIdx.x;
  const float* xr = x + (size_t)row * D_MODEL;
  float vreg[7]; int dreg[7];
  int cnt = 0;
  float ss = 0.f;
  for (int i = threadIdx.x; i < D_MODEL; i += 256){
    float v = xr[i];
    int e = i % 5, c = (i / 5) % 62, f = i / 310;
    int d = (c * 5 + f) * 5 + e;
    vreg[cnt] = v; dreg[cnt] = d; cnt++;
    ss = fmaf(v, v, ss);
    h[(size_t)row * D_MODEL + d] = v;
  }
  __shared__ float red[4];
  __shared__ float sscale;
  int lane = threadIdx.x & 63, wv = threadIdx.x >> 6;
  #pragma unroll
  for (int o = 32; o > 0; o >>= 1) ss += __shfl_down(ss, o, 64);
  if (lane == 0) red[wv] = ss;
  __syncthreads();
  if (threadIdx.x == 0){
    float t = red[0] + red[1] + red[2] + red[3];
    sscale = 1.0f / sqrtf(t / (float)D_MODEL + EPSV);
  }
  __syncthreads();
  float sc = sscale;
  __hip_bfloat16* orow = hn + (size_t)row * KD;
  for (int k = 0; k < cnt; k++)
    orow[dreg[k]] = __float2bfloat16(vreg[k] * sc * w[dreg[k]]);
  for (int i = D_MODEL + threadIdx.x; i < KD; i += 256)
    orow[i] = __float2bfloat16(0.f);
}

// ---------------- fused residual-reduce (4 bf16 partials) + rmsnorm
__global__ __launch_bounds__(256)
void k_rms_res(float* __restrict__ h, const __hip_bfloat16* __restrict__ part,
               const float* __restrict__ w, __hip_bfloat16* __restrict__ hn){
  int row = blockIdx.x;
  size_t hb = (size_t)row * D_MODEL;
  float vreg[7];
  int cnt = 0;
  float ss = 0.f;
  for (int i = threadIdx.x; i < D_MODEL; i += 256){
    float v = h[hb + i];
    #pragma unroll
    for (int p = 0; p < 4; p++)
      v += __bfloat162float(part[(size_t)p * NBS * D_MODEL + hb + i]);
    h[hb + i] = v;
    vreg[cnt++] = v;
    ss = fmaf(v, v, ss);
  }
  __shared__ float red[4];
  __shared__ float sscale;
  int lane = threadIdx.x & 63, wv = threadIdx.x >> 6;
  #pragma unroll
  for (int o = 32; o > 0; o >>= 1) ss += __shfl_down(ss, o, 64);
  if (lane == 0) red[wv] = ss;
  __syncthreads();
  if (threadIdx.x == 0){
    float t = red[0] + red[1] + red[2] + red[3];
    sscale = 1.0f / sqrtf(t / (float)D_MODEL + EPSV);
  }
  __syncthreads();
  float sc = sscale;
  __hip_bfloat16* orow = hn + (size_t)row * KD;
  for (int k = 0; k < cnt; k++){
    int i = threadIdx.x + k * 256;
    orow[i] = __float2bfloat16(vreg[k] * sc * w[i]);
  }
  for (int i = D_MODEL + threadIdx.x; i < KD; i += 256)
    orow[i] = __float2bfloat16(0.f);
}

// ---------------- cast+pad quad helper (vectorized 8B store)
__device__ __forceinline__ void cast4(const float* __restrict__ src,
                                      __hip_bfloat16* __restrict__ dst,
                                      int q, int N, int K, int Kp){
  int i4 = q * 4;
  int row = i4 / Kp;
  int col = i4 % Kp;
  const float* srow = src + (size_t)row * K;
  ushort4 o;
  o.x = bfbits((row < N && col + 0 < K) ? srow[col + 0] : 0.f);
  o.y = bfbits((row < N && col + 1 < K) ? srow[col + 1] : 0.f);
  o.z = bfbits((row < N && col + 2 < K) ? srow[col + 2] : 0.f);
  o.w = bfbits((row < N && col + 3 < K) ? srow[col + 3] : 0.f);
  *(ushort4*)(dst + i4) = o;
}

// ---------------- one-shot per-layer prep: weight casts + A_t (+ layer0 extras)
__global__ __launch_bounds__(256)
void k_prep(const float* __restrict__ ipw, const float* __restrict__ xpw,
            const float* __restrict__ dtw, const float* __restrict__ opw,
            const float* __restrict__ alog,
            const float* __restrict__ lmw, const float* __restrict__ embw,
            __hip_bfloat16* __restrict__ ipb, __hip_bfloat16* __restrict__ xpb,
            __hip_bfloat16* __restrict__ dtwb, __hip_bfloat16* __restrict__ opb,
            float* __restrict__ A_t,
            __hip_bfloat16* __restrict__ lmb,
            float* __restrict__ emb_t, float* __restrict__ sumw,
            float* __restrict__ stats, int l0){
  int idx = blockIdx.x * 256 + threadIdx.x;
  if (idx < QIP){ cast4(ipw, ipb, idx, 2 * ED, D_MODEL, KD); return; } idx -= QIP;
  if (idx < QXP){ cast4(xpw, xpb, idx, DBC_R, ED, KE); return; } idx -= QXP;
  if (idx < QDT){ cast4(dtw, dtwb, idx, ED, DTR, KDT); return; } idx -= QDT;
  if (idx < QOP){ cast4(opw, opb, idx, D_MODEL, ED, KE); return; } idx -= QOP;
  if (idx < AEL){
    int n = idx / ED, ch = idx % ED;
    A_t[idx] = -expf(alog[(size_t)ch * NSTATE + n]);
    return;
  } idx -= AEL;
  if (!l0) return;
  if (idx < QLM){ cast4(lmw, lmb, idx, VOCAB, D_MODEL, KD); return; } idx -= QLM;
  if (idx < TEL){
    int v = idx >> 8, o = idx & 255;
    emb_t[idx] = embw[(size_t)o * VOCAB + v];
    return;
  } idx -= TEL;
  if (idx < 256){
    const float* r = embw + (size_t)idx * VOCAB;
    float s = 0.f;
    for (int v = 0; v < VOCAB; v++) s += r[v];
    sumw[idx] = s;
    return;
  } idx -= 256;
  if (idx < 2) stats[idx] = 0.f;
}

// ---------------- 2-phase double-buffered bf16 MFMA NT GEMM
// + XCD-chunked swizzle + LDS chunk-XOR bank swizzle (source-permuted, rule #21)
// C[M,Nld] = A[M,Kp] * B[Npad,Kp]^T over K chunk blockIdx.z.
// PARTIAL -> offset output by blockIdx.z*(gy*128*Nld). DUAL -> z==1 writes Cv1.
template<int SPLITS, bool OUT_BF16, bool PARTIAL, bool DUAL>
__global__ __launch_bounds__(256)
void k_gemm2(const __hip_bfloat16* __restrict__ A, const __hip_bfloat16* __restrict__ B,
             void* Cv, void* Cv1, int Kp, int Nld, int Nreal){
  __shared__ short Al[2][4096];   // [buf][128 rows x 32 k]
  __shared__ short Bl[2][4096];
  // XCD-aware bijective swizzle (m204), column-major decode.
  const int gx = gridDim.x, gy = gridDim.y;
  const int nwg = gx * gy;
  const int wg = blockIdx.y * gx + blockIdx.x;
  const int q = nwg >> 3, r = nwg & 7;
  const int xcd = wg & 7, off = wg >> 3;
  const int nid = (xcd < r ? xcd * (q + 1) : r * (q + 1) + (xcd - r) * q) + off;
  const int bm = (nid % gy) * 128;
  const int bn = (nid / gy) * 128;

  const int t = threadIdx.x;
  const int tt8 = t * 8;

  int kb = 0, ke = Kp;
  if (SPLITS > 1){
    int Kc = ((Kp / SPLITS + 31) / 32) * 32;
    kb = blockIdx.z * Kc;
    ke = min(kb + Kc, Kp);
    if (kb >= ke) return;
  }
  const int nt = (ke - kb) / 32;

  // LDS bank swizzle: logical k-chunk kc stored at physical chunk kc^(row&3).
  const int cg = ((t & 3) ^ ((t >> 2) & 3)) * 8;
  const short* Ab = (const short*)A;
  const short* Bb = (const short*)B;
  const short* ga0 = Ab + (size_t)(bm + (t >> 2)) * Kp + cg;
  const short* ga1 = Ab + (size_t)(bm + 64 + (t >> 2)) * Kp + cg;
  const short* gb0 = Bb + (size_t)(bn + (t >> 2)) * Kp + cg;
  const short* gb1 = Bb + (size_t)(bn + 64 + (t >> 2)) * Kp + cg;

  const int l = t & 63;
  const int wid = t >> 6;
  const int wr = wid >> 1, wc = wid & 1;
  const int fr = l & 15;
  const int cc = ((l >> 4) ^ (l & 3)) * 8;   // physical chunk for this lane's rows

  f32x4 acc[4][4] = {};

#define STAGE(buf, kof) do{ \
    gload16(ga0 + (kof), &Al[buf][tt8]); \
    gload16(ga1 + (kof), &Al[buf][2048 + tt8]); \
    gload16(gb0 + (kof), &Bl[buf][tt8]); \
    gload16(gb1 + (kof), &Bl[buf][2048 + tt8]); }while(0)

  STAGE(0, kb);
  __syncthreads();
  int cur = 0;
  for (int it = 0; it < nt; ++it){
    if (it + 1 < nt) STAGE(cur ^ 1, kb + (it + 1) * 32);
    bf16x8 af[4], bfr[4];
    #pragma unroll
    for (int m = 0; m < 4; m++)
      af[m] = *(const bf16x8*)&Al[cur][(wr * 64 + m * 16 + fr) * 32 + cc];
    #pragma unroll
    for (int n = 0; n < 4; n++)
      bfr[n] = *(const bf16x8*)&Bl[cur][(wc * 64 + n * 16 + fr) * 32 + cc];
    #pragma unroll
    for (int m = 0; m < 4; m++)
      #pragma unroll
      for (int n = 0; n < 4; n++)
        acc[m][n] = __builtin_amdgcn_mfma_f32_16x16x32_bf16(af[m], bfr[n], acc[m][n], 0, 0, 0);
    if (it + 1 < nt){ __syncthreads(); cur ^= 1; }
  }
#undef STAGE

  float* Cf = (float*)Cv;
  __hip_bfloat16* Cb = (__hip_bfloat16*)Cv;
  if (DUAL && blockIdx.z == 1) Cb = (__hip_bfloat16*)Cv1;
  if (PARTIAL){
    const size_t pstride = (size_t)gy * 128 * Nld;
    if (OUT_BF16) Cb += (size_t)blockIdx.z * pstride;
    else          Cf += (size_t)blockIdx.z * pstride;
  }
  const int r0 = (l >> 4) * 4;
  #pragma unroll
  for (int m = 0; m < 4; m++){
    #pragma unroll
    for (int n = 0; n < 4; n++){
      int col = bn + wc * 64 + n * 16 + fr;
      if (col < Nreal){
        size_t base = (size_t)(bm + wr * 64 + m * 16 + r0) * Nld + col;
        #pragma unroll
        for (int j = 0; j < 4; j++){
          float v = acc[m][n][j];
          size_t o = base + (size_t)j * Nld;
          if (OUT_BF16) Cb[o] = __float2bfloat16(v);
          else          Cf[o] = v;
        }
      }
    }
  }
}

// ---------------- conv+silu over summed in_proj partials; also writes summed z into xz0
__global__ void k_conv_silu2(__hip_bfloat16* __restrict__ xz0,
                             const __hip_bfloat16* __restrict__ xz1,
                             const float* __restrict__ cw, const float* __restrict__ cb,
                             __hip_bfloat16* __restrict__ xc_b){
  int idx = blockIdx.x * 256 + threadIdx.x;
  if (idx >= B_SZ * KE) return;
  int ch = idx % KE;
  int b  = idx / KE;
  size_t ob = (size_t)b * SEQ * KE + ch;
  if (ch >= ED){
    __hip_bfloat16 z = __float2bfloat16(0.f);
    xc_b[ob] = z; xc_b[ob + KE] = z; xc_b[ob + 2 * KE] = z;
    return;
  }
  size_t rb = (size_t)b * SEQ * NIP;
  const __hip_bfloat16* p0 = xz0 + rb + ch;
  const __hip_bfloat16* p1 = xz1 + rb + ch;
  float x0 = __bfloat162float(p0[0])       + __bfloat162float(p1[0]);
  float x1 = __bfloat162float(p0[NIP])     + __bfloat162float(p1[NIP]);
  float x2 = __bfloat162float(p0[2 * NIP]) + __bfloat162float(p1[2 * NIP]);
  // z-part: sum partials, write back into xz0
  __hip_bfloat16* q0 = xz0 + rb + ED + ch;
  const __hip_bfloat16* q1 = xz1 + rb + ED + ch;
  #pragma unroll
  for (int t = 0; t < SEQ; t++){
    float zv = __bfloat162float(q0[(size_t)t * NIP]) + __bfloat162float(q1[(size_t)t * NIP]);
    q0[(size_t)t * NIP] = __float2bfloat16(zv);
  }
  const float* w = cw + (size_t)ch * 4;
  float w1 = w[1], w2 = w[2], w3 = w[3];
  float bb = cb[ch];
  float s0 = silu_f(fmaf(w3, x0, bb));
  float s1 = silu_f(fmaf(w2, x0, fmaf(w3, x1, bb)));
  float s2 = silu_f(fmaf(w1, x0, fmaf(w2, x1, fmaf(w3, x2, bb))));
  xc_b[ob]          = __float2bfloat16(s0);
  xc_b[ob + KE]     = __float2bfloat16(s1);
  xc_b[ob + 2 * KE] = __float2bfloat16(s2);
}

// ---------------- x_proj split-K reduce: part[8][NBS][256] -> dbc fp32 + dbc_b bf16
__global__ __launch_bounds__(256)
void k_xred(const float* __restrict__ part, float* __restrict__ dbc,
            __hip_bfloat16* __restrict__ dbc_b){
  int idx = blockIdx.x * 256 + threadIdx.x;
  if (idx >= NBS * DBC_LD) return;
  float s = 0.f;
  #pragma unroll
  for (int p = 0; p < 8; p++) s += part[(size_t)p * NBS * DBC_LD + idx];
  dbc[idx] = s;
  int c = idx & 255, row = idx >> 8;
  if (c < KDT) dbc_b[(size_t)row * KDT + c] = __float2bfloat16(c < DTR ? s : 0.f);
}

// ---------------- lean scan: softplus(delta_b+bias) + SSM + D skip + z gate, in-place on xc_b
__global__ __launch_bounds__(256)
void k_scan2(const __hip_bfloat16* __restrict__ delta_b, const float* __restrict__ dbc,
             const float* __restrict__ dtb, const float* __restrict__ A_t,
             const float* __restrict__ Dp, const __hip_bfloat16* __restrict__ xz,
             __hip_bfloat16* __restrict__ xc_b){
  __shared__ float sB[SEQ][NSTATE], sC[SEQ][NSTATE];
  int b = blockIdx.y;
  if (threadIdx.x < SEQ * 2 * NSTATE){
    int t = threadIdx.x / (2 * NSTATE), r = threadIdx.x % (2 * NSTATE);
    float v = dbc[(size_t)(b * SEQ + t) * DBC_LD + DTR + r];
    if (r < NSTATE) sB[t][r] = v; else sC[t][r - NSTATE] = v;
  }
  __syncthreads();
  int ch = blockIdx.x * 256 + threadIdx.x;
  if (ch >= ED) return;

  float bias = dtb[ch];
  float dlt[SEQ];
  #pragma unroll
  for (int t = 0; t < SEQ; t++){
    float acc = __bfloat162float(delta_b[(size_t)(b * SEQ + t) * NDT + ch]) + bias;
    dlt[t] = (acc > 20.f) ? acc : log1pf(expf(acc));
  }

  size_t ob = (size_t)b * SEQ * KE + ch;
  float xcv[SEQ] = { __bfloat162float(xc_b[ob]),
                     __bfloat162float(xc_b[ob + KE]),
                     __bfloat162float(xc_b[ob + 2 * KE]) };
  float y[SEQ] = {0.f, 0.f, 0.f};
  #pragma unroll
  for (int n = 0; n < NSTATE; n++){
    float Av = A_t[(size_t)n * ED + ch];
    float hs = 0.f;
    #pragma unroll
    for (int t = 0; t < SEQ; t++){
      float dA = expf(dlt[t] * Av);
      hs = fmaf(dA, hs, dlt[t] * sB[t][n] * xcv[t]);
      y[t] = fmaf(hs, sC[t][n], y[t]);
    }
  }
  float dp = Dp[ch];
  const __hip_bfloat16* zbase = xz + (size_t)b * SEQ * NIP + ED + ch;
  #pragma unroll
  for (int t = 0; t < SEQ; t++){
    float z = __bfloat162float(zbase[(size_t)t * NIP]);
    float yy = fmaf(dp, xcv[t], y[t]);
    xc_b[ob + (size_t)t * KE] = __float2bfloat16(yy * silu_f(z));
  }
}

// ---------------- lm partial reduce -> logits, + stats (raw sum, sumsq) via atomics
__global__ __launch_bounds__(256)
void k_statsred(const float* __restrict__ part, float* __restrict__ logits,
                float* __restrict__ stats){
  float s = 0.f, ss = 0.f;
  for (int i = blockIdx.x * 256 + threadIdx.x; i < NBS * VOCAB; i += gridDim.x * 256){
    float v = 0.f;
    #pragma unroll
    for (int p = 0; p < 4; p++) v += part[(size_t)p * NBS * VOCAB + i];
    logits[i] = v;
    s += v; ss = fmaf(v, v, ss);
  }
  #pragma unroll
  for (int o = 32; o > 0; o >>= 1){ s += __shfl_down(s, o, 64); ss += __shfl_down(ss, o, 64); }
  __shared__ float rs[4], rss[4];
  int lane = threadIdx.x & 63, wv = threadIdx.x >> 6;
  if (lane == 0){ rs[wv] = s; rss[wv] = ss; }
  __syncthreads();
  if (threadIdx.x == 0){
    atomicAdd(&stats[0], rs[0] + rs[1] + rs[2] + rs[3]);
    atomicAdd(&stats[1], rss[0] + rss[1] + rss[2] + rss[3]);
  }
}

// ---------------- fused: proj = logits @ emb^T, BN normalize, write out[b,f,s,o]
__global__ __launch_bounds__(256)
void k_projfinal(const float* __restrict__ logits, const float* __restrict__ emb_t,
                 const float* __restrict__ sumw, const float* __restrict__ stats,
                 const float* __restrict__ bnw, const float* __restrict__ bnb,
                 const float* __restrict__ embb, float* __restrict__ out){
  __shared__ float row[VOCAB];
  int r = blockIdx.x;            // b*SEQ + s
  int o = threadIdx.x;           // 0..255
  if (o < VOCAB) row[o] = logits[(size_t)r * VOCAB + o];
  __syncthreads();
  float p = 0.f;
  #pragma unroll 8
  for (int v = 0; v < VOCAB; v++) p = fmaf(row[v], emb_t[v * 256 + o], p);
  const float invN = 1.0f / (float)(NBS * VOCAB);
  float mean = stats[0] * invN;
  float var  = stats[1] * invN - mean * mean;
  float rstd = rsqrtf(var + EPSV);
  int b = r / SEQ, s = r % SEQ;
  float sw = sumw[o];
  float base = rstd * (p - mean * sw);
  float eb = embb[o];
  #pragma unroll
  for (int f = 0; f < 5; f++){
    out[(((size_t)(b * 5 + f)) * SEQ + s) * 256 + o] = bnw[f] * base + bnb[f] * sw + eb;
  }
}

extern "C" void kernel_launch(void* const* d_in, const int* in_sizes, int n_in,
                              void* d_out, int out_size, void* d_ws, size_t ws_size,
                              hipStream_t stream) {
  const float* x          = (const float*)d_in[0];
  const float* in_proj_w  = (const float*)d_in[1];
  const float* conv_w     = (const float*)d_in[2];
  const float* conv_b     = (const float*)d_in[3];
  const float* x_proj_w   = (const float*)d_in[4];
  const float* dt_proj_w  = (const float*)d_in[5];
  const float* dt_proj_b  = (const float*)d_in[6];
  const float* A_log      = (const float*)d_in[7];
  const float* D_param    = (const float*)d_in[8];
  const float* out_proj_w = (const float*)d_in[9];
  const float* norm_w     = (const float*)d_in[10];
  const float* normf_w    = (const float*)d_in[11];
  const float* lm_head_w  = (const float*)d_in[12];
  const float* bn_w       = (const float*)d_in[13];
  const float* bn_b       = (const float*)d_in[14];
  const float* emb_w      = (const float*)d_in[15];
  const float* emb_b      = (const float*)d_in[16];

  float* ws = (float*)d_ws;
  float* h      = ws;                                   // NBS*D_MODEL
  float* dbc    = h      + (size_t)NBS * D_MODEL;       // NBS*DBC_LD
  float* logits = dbc    + (size_t)NBS * DBC_LD;        // NBS*VOCAB
  float* sumw   = logits + (size_t)NBS * VOCAB;         // 256
  float* stats  = sumw   + 256;                         // 2
  float* A_t    = stats  + 2;                           // NSTATE*ED
  float* emb_t  = A_t    + (size_t)NSTATE * ED;         // VOCAB*256
  // shared partial arena (disjoint lifetimes):
  //  ipz1 (NBS*NIP bf16 = 19.27MB)  < xpart (8*NBS*256 f32 = 12.6MB)
  //  < opart (4*NBS*1550 bf16 = 19.05MB) < lmpart (4*NBS*128 f32 = 3.1MB)
  float* spart  = emb_t  + (size_t)VOCAB * 256;
  size_t spart_f = (size_t)NBS * NIP / 2;               // bf16 ipz1 in floats (largest)
  float* xpart  = spart;
  float* lmpart = spart;
  __hip_bfloat16* opart = (__hip_bfloat16*)spart;
  __hip_bfloat16* ipz1  = (__hip_bfloat16*)spart;
  __hip_bfloat16* xz_b   = (__hip_bfloat16*)(spart + spart_f); // NBS*NIP
  __hip_bfloat16* hn_b   = xz_b   + (size_t)NBS * NIP;  // NBS*KD
  __hip_bfloat16* xc_b   = hn_b   + (size_t)NBS * KD;   // NBS*KE
  __hip_bfloat16* dbc_b  = xc_b   + (size_t)NBS * KE;   // NBS*KDT
  __hip_bfloat16* dlt_b  = dbc_b  + (size_t)NBS * KDT;  // NBS*NDT
  __hip_bfloat16* ipb    = dlt_b  + (size_t)NBS * NDT;  // NIP*KD
  __hip_bfloat16* xpb    = ipb    + (size_t)NIP * KD;   // NXP*KE
  __hip_bfloat16* dtwb   = xpb    + (size_t)NXP * KE;   // NDT*KDT
  __hip_bfloat16* opb    = dtwb   + (size_t)NDT * KDT;  // NOP*KE
  __hip_bfloat16* lmb    = opb    + (size_t)NOP * KE;   // VOCAB*KD
  size_t need = (size_t)((char*)(lmb + (size_t)VOCAB * KD) - (char*)ws);
  if (ws_size < need) return;

  for (int l = 0; l < 2; l++){
    const float* ipw = in_proj_w  + (size_t)l * 2 * ED * D_MODEL;
    const float* cw  = conv_w     + (size_t)l * ED * 4;
    const float* cb  = conv_b     + (size_t)l * ED;
    const float* xpw = x_proj_w   + (size_t)l * DBC_R * ED;
    const float* dtw = dt_proj_w  + (size_t)l * ED * DTR;
    const float* dtb = dt_proj_b  + (size_t)l * ED;
    const float* al  = A_log      + (size_t)l * ED * NSTATE;
    const float* dp  = D_param    + (size_t)l * ED;
    const float* opw = out_proj_w + (size_t)l * D_MODEL * ED;
    const float* nw  = norm_w     + (size_t)l * D_MODEL;

    // per-layer prep: weight casts + A_t (+ layer0: lm cast, emb_t, sumw, stats zero)
    k_prep<<<cdiv_h(l == 0 ? PREP_N0 : PREP_N1, 256), 256, 0, stream>>>(
        ipw, xpw, dtw, opw, al, lm_head_w, emb_w,
        ipb, xpb, dtwb, opb, A_t, lmb, emb_t, sumw, stats, l == 0 ? 1 : 0);

    if (l == 0){
      // fused permute + rmsnorm (layer 0)
      k_perm_rms<<<NBS, 256, 0, stream>>>(x, nw, h, hn_b);
    } else {
      // fused residual-reduce (prev layer opart) + rmsnorm
      k_rms_res<<<NBS, 256, 0, stream>>>(h, opart, nw, hn_b);
    }

    // in_proj (split-K 2, DUAL bf16 partials xz_b / ipz1)
    k_gemm2<2, true, false, true><<<dim3(NIP / 128, NBS / 128, 2), 256, 0, stream>>>(
        hn_b, ipb, xz_b, ipz1, KD, NIP, NIP);

    // conv+silu over summed partials; writes summed z into xz_b
    k_conv_silu2<<<cdiv_h(B_SZ * KE, 256), 256, 0, stream>>>(xz_b, ipz1, cw, cb, xc_b);

    // x_proj (split-K 8, fp32 partials)
    k_gemm2<8, false, true, false><<<dim3(NXP / 128, NBS / 128, 8), 256, 0, stream>>>(
        xc_b, xpb, xpart, nullptr, KE, DBC_LD, DBC_LD);
    k_xred<<<cdiv_h(NBS * DBC_LD, 256), 256, 0, stream>>>(xpart, dbc, dbc_b);

    // dt_proj: dlt_b[1536,3200](bf16) = dbc_b[1536,128] @ dtwb^T
    k_gemm2<1, true, false, false><<<dim3(NDT / 128, NBS / 128, 1), 256, 0, stream>>>(
        dbc_b, dtwb, dlt_b, nullptr, KDT, NDT, NDT);

    k_scan2<<<dim3(cdiv_h(ED, 256), B_SZ), 256, 0, stream>>>(
        dlt_b, dbc, dtb, A_t, dp, xz_b, xc_b);

    // out_proj (split-K 4, bf16 partials)
    k_gemm2<4, true, true, false><<<dim3(NOP / 128, NBS / 128, 4), 256, 0, stream>>>(
        xc_b, opb, opart, nullptr, KE, D_MODEL, D_MODEL);
  }

  // final: fused residual-reduce + rmsnorm, lm head (split-K 4, fp32 partials)
  k_rms_res<<<NBS, 256, 0, stream>>>(h, opart, normf_w, hn_b);
  k_gemm2<4, false, true, false><<<dim3(1, NBS / 128, 4), 256, 0, stream>>>(
      hn_b, lmb, lmpart, nullptr, KD, VOCAB, VOCAB);
  k_statsred<<<192, 256, 0, stream>>>(lmpart, logits, stats);

  k_projfinal<<<NBS, 256, 0, stream>>>(logits, emb_t, sumw, stats,
                                       bn_w, bn_b, emb_b, (float*)d_out);
}

// Round 9
// 480.578 us; speedup vs baseline: 1.1867x; 1.0240x over previous
//
#include <hip/hip_runtime.h>
#include <hip/hip_bf16.h>
#include <math.h>

#define B_SZ 512
#define SEQ 3
#define D_MODEL 1550
#define ED 3100
#define NSTATE 16
#define DTR 97
#define DBC_R 129   // DTR + 2*NSTATE
#define VOCAB 128
#define NBS (B_SZ*SEQ)       // 1536
#define EPSV 1e-5f

// padded dims
#define KD 1600     // D_MODEL -> 64*25
#define KE 3136     // ED -> 64*49
#define NIP 6272    // 2*ED=6200 -> 49*128
#define NXP 256     // 129 -> 2*128
#define NOP 1664    // 1550 -> 13*128
#define NDT 3200    // ED -> 25*128
#define KDT 128     // DTR -> 128
#define DBC_LD 256

// prep job sizes (quads of 4 elems unless noted)
#define QIP 2508800   // NIP*KD/4
#define QXP 200704    // NXP*KE/4
#define QDT 102400    // NDT*KDT/4
#define QOP 1304576   // NOP*KE/4
#define AEL 49600     // NSTATE*ED scalars
#define QLM 51200     // VOCAB*KD/4
#define TEL 32768     // VOCAB*256 scalars (emb transpose)
#define PREP_N1 4166080   // QIP+QXP+QDT+QOP+AEL
#define PREP_N0 4250306   // PREP_N1+QLM+TEL+256+2

static inline int cdiv_h(int a, int b){ return (a + b - 1) / b; }

__device__ __forceinline__ float silu_f(float x){ return x / (1.0f + expf(-x)); }

using bf16x8 = __attribute__((ext_vector_type(8))) short;
using f32x4  = __attribute__((ext_vector_type(4))) float;

__device__ __forceinline__ void gload16(const void* g, void* l){
  __builtin_amdgcn_global_load_lds(
      (const __attribute__((address_space(1))) unsigned int*)g,
      (__attribute__((address_space(3))) unsigned int*)l,
      16, 0, 0);
}

__device__ __forceinline__ unsigned short bfbits(float v){
  __hip_bfloat16 b = __float2bfloat16(v);
  return *(unsigned short*)&b;
}

// ---------------- fused permute + layer0 rmsnorm
__global__ __launch_bounds__(256)
void k_perm_rms(const float* __restrict__ x, const float* __restrict__ w,
                float* __restrict__ h, __hip_bfloat16* __restrict__ hn){
  int row = blockIdx.x;
  const float* xr = x + (size_t)row * D_MODEL;
  float vreg[7]; int dreg[7];
  int cnt = 0;
  float ss = 0.f;
  for (int i = threadIdx.x; i < D_MODEL; i += 256){
    float v = xr[i];
    int e = i % 5, c = (i / 5) % 62, f = i / 310;
    int d = (c * 5 + f) * 5 + e;
    vreg[cnt] = v; dreg[cnt] = d; cnt++;
    ss = fmaf(v, v, ss);
    h[(size_t)row * D_MODEL + d] = v;
  }
  __shared__ float red[4];
  __shared__ float sscale;
  int lane = threadIdx.x & 63, wv = threadIdx.x >> 6;
  #pragma unroll
  for (int o = 32; o > 0; o >>= 1) ss += __shfl_down(ss, o, 64);
  if (lane == 0) red[wv] = ss;
  __syncthreads();
  if (threadIdx.x == 0){
    float t = red[0] + red[1] + red[2] + red[3];
    sscale = 1.0f / sqrtf(t / (float)D_MODEL + EPSV);
  }
  __syncthreads();
  float sc = sscale;
  __hip_bfloat16* orow = hn + (size_t)row * KD;
  for (int k = 0; k < cnt; k++)
    orow[dreg[k]] = __float2bfloat16(vreg[k] * sc * w[dreg[k]]);
  for (int i = D_MODEL + threadIdx.x; i < KD; i += 256)
    orow[i] = __float2bfloat16(0.f);
}

// ---------------- fused residual-reduce (4 bf16 partials) + rmsnorm
__global__ __launch_bounds__(256)
void k_rms_res(float* __restrict__ h, const __hip_bfloat16* __restrict__ part,
               const float* __restrict__ w, __hip_bfloat16* __restrict__ hn){
  int row = blockIdx.x;
  size_t hb = (size_t)row * D_MODEL;
  float vreg[7];
  int cnt = 0;
  float ss = 0.f;
  for (int i = threadIdx.x; i < D_MODEL; i += 256){
    float v = h[hb + i];
    #pragma unroll
    for (int p = 0; p < 4; p++)
      v += __bfloat162float(part[(size_t)p * NBS * D_MODEL + hb + i]);
    h[hb + i] = v;
    vreg[cnt++] = v;
    ss = fmaf(v, v, ss);
  }
  __shared__ float red[4];
  __shared__ float sscale;
  int lane = threadIdx.x & 63, wv = threadIdx.x >> 6;
  #pragma unroll
  for (int o = 32; o > 0; o >>= 1) ss += __shfl_down(ss, o, 64);
  if (lane == 0) red[wv] = ss;
  __syncthreads();
  if (threadIdx.x == 0){
    float t = red[0] + red[1] + red[2] + red[3];
    sscale = 1.0f / sqrtf(t / (float)D_MODEL + EPSV);
  }
  __syncthreads();
  float sc = sscale;
  __hip_bfloat16* orow = hn + (size_t)row * KD;
  for (int k = 0; k < cnt; k++){
    int i = threadIdx.x + k * 256;
    orow[i] = __float2bfloat16(vreg[k] * sc * w[i]);
  }
  for (int i = D_MODEL + threadIdx.x; i < KD; i += 256)
    orow[i] = __float2bfloat16(0.f);
}

// ---------------- cast+pad quad helper (vectorized 8B store)
__device__ __forceinline__ void cast4(const float* __restrict__ src,
                                      __hip_bfloat16* __restrict__ dst,
                                      int q, int N, int K, int Kp){
  int i4 = q * 4;
  int row = i4 / Kp;
  int col = i4 % Kp;
  const float* srow = src + (size_t)row * K;
  ushort4 o;
  o.x = bfbits((row < N && col + 0 < K) ? srow[col + 0] : 0.f);
  o.y = bfbits((row < N && col + 1 < K) ? srow[col + 1] : 0.f);
  o.z = bfbits((row < N && col + 2 < K) ? srow[col + 2] : 0.f);
  o.w = bfbits((row < N && col + 3 < K) ? srow[col + 3] : 0.f);
  *(ushort4*)(dst + i4) = o;
}

// ---------------- one-shot per-layer prep: weight casts + A_t (+ layer0 extras)
__global__ __launch_bounds__(256)
void k_prep(const float* __restrict__ ipw, const float* __restrict__ xpw,
            const float* __restrict__ dtw, const float* __restrict__ opw,
            const float* __restrict__ alog,
            const float* __restrict__ lmw, const float* __restrict__ embw,
            __hip_bfloat16* __restrict__ ipb, __hip_bfloat16* __restrict__ xpb,
            __hip_bfloat16* __restrict__ dtwb, __hip_bfloat16* __restrict__ opb,
            float* __restrict__ A_t,
            __hip_bfloat16* __restrict__ lmb,
            float* __restrict__ emb_t, float* __restrict__ sumw,
            float* __restrict__ stats, int l0){
  int idx = blockIdx.x * 256 + threadIdx.x;
  if (idx < QIP){ cast4(ipw, ipb, idx, 2 * ED, D_MODEL, KD); return; } idx -= QIP;
  if (idx < QXP){ cast4(xpw, xpb, idx, DBC_R, ED, KE); return; } idx -= QXP;
  if (idx < QDT){ cast4(dtw, dtwb, idx, ED, DTR, KDT); return; } idx -= QDT;
  if (idx < QOP){ cast4(opw, opb, idx, D_MODEL, ED, KE); return; } idx -= QOP;
  if (idx < AEL){
    int n = idx / ED, ch = idx % ED;
    A_t[idx] = -expf(alog[(size_t)ch * NSTATE + n]);
    return;
  } idx -= AEL;
  if (!l0) return;
  if (idx < QLM){ cast4(lmw, lmb, idx, VOCAB, D_MODEL, KD); return; } idx -= QLM;
  if (idx < TEL){
    int v = idx >> 8, o = idx & 255;
    emb_t[idx] = embw[(size_t)o * VOCAB + v];
    return;
  } idx -= TEL;
  if (idx < 256){
    const float* r = embw + (size_t)idx * VOCAB;
    float s = 0.f;
    for (int v = 0; v < VOCAB; v++) s += r[v];
    sumw[idx] = s;
    return;
  } idx -= 256;
  if (idx < 2) stats[idx] = 0.f;
}

// ---------------- 3-stage ring-buffer bf16 MFMA NT GEMM (counted vmcnt, 1 barrier/K-step)
// + XCD-chunked swizzle + LDS chunk-XOR bank swizzle (source-permuted)
// C[M,Nld] = A[M,Kp] * B[Npad,Kp]^T over K chunk blockIdx.z.
template<int SPLITS, bool OUT_BF16, bool PARTIAL>
__global__ __launch_bounds__(256)
void k_gemm3(const __hip_bfloat16* __restrict__ A, const __hip_bfloat16* __restrict__ B,
             void* Cv, int Kp, int Nld, int Nreal){
  __shared__ short Al[3][4096];   // ring: [buf][128 rows x 32 k]
  __shared__ short Bl[3][4096];
  // XCD-aware bijective swizzle (m204), column-major decode.
  const int gx = gridDim.x, gy = gridDim.y;
  const int nwg = gx * gy;
  const int wg = blockIdx.y * gx + blockIdx.x;
  const int q = nwg >> 3, r = nwg & 7;
  const int xcd = wg & 7, off = wg >> 3;
  const int nid = (xcd < r ? xcd * (q + 1) : r * (q + 1) + (xcd - r) * q) + off;
  const int bm = (nid % gy) * 128;
  const int bn = (nid / gy) * 128;

  const int t = threadIdx.x;
  const int tt8 = t * 8;

  int kb = 0, ke = Kp;
  if (SPLITS > 1){
    int Kc = ((Kp / SPLITS + 31) / 32) * 32;
    kb = blockIdx.z * Kc;
    ke = min(kb + Kc, Kp);
    if (kb >= ke) return;
  }
  const int nt = (ke - kb) / 32;

  // LDS bank swizzle: logical k-chunk kc stored at physical chunk kc^(row&3).
  const int cg = ((t & 3) ^ ((t >> 2) & 3)) * 8;
  const short* Ab = (const short*)A;
  const short* Bb = (const short*)B;
  const short* ga0 = Ab + (size_t)(bm + (t >> 2)) * Kp + cg;
  const short* ga1 = Ab + (size_t)(bm + 64 + (t >> 2)) * Kp + cg;
  const short* gb0 = Bb + (size_t)(bn + (t >> 2)) * Kp + cg;
  const short* gb1 = Bb + (size_t)(bn + 64 + (t >> 2)) * Kp + cg;

  const int l = t & 63;
  const int wid = t >> 6;
  const int wr = wid >> 1, wc = wid & 1;
  const int fr = l & 15;
  const int cc = ((l >> 4) ^ (l & 3)) * 8;   // physical chunk for this lane's rows

  f32x4 acc[4][4] = {};

#define STAGE(buf, kof) do{ \
    gload16(ga0 + (kof), &Al[buf][tt8]); \
    gload16(ga1 + (kof), &Al[buf][2048 + tt8]); \
    gload16(gb0 + (kof), &Bl[buf][tt8]); \
    gload16(gb1 + (kof), &Bl[buf][2048 + tt8]); }while(0)

  STAGE(0, kb);
  if (nt > 1) STAGE(1, kb + 32);
  int bsel = 0, snext = 2;
  for (int it = 0; it < nt; ++it){
    // wait for tile it (oldest 4 loads); tile it+1's 4 stay in flight
    if (it + 1 < nt) asm volatile("s_waitcnt vmcnt(4)" ::: "memory");
    else             asm volatile("s_waitcnt vmcnt(0)" ::: "memory");
    __builtin_amdgcn_s_barrier();
    asm volatile("" ::: "memory");
    __builtin_amdgcn_sched_barrier(0);
    if (it + 2 < nt) STAGE(snext, kb + (it + 2) * 32);
    bf16x8 af[4], bfr[4];
    #pragma unroll
    for (int m = 0; m < 4; m++)
      af[m] = *(const bf16x8*)&Al[bsel][(wr * 64 + m * 16 + fr) * 32 + cc];
    #pragma unroll
    for (int n = 0; n < 4; n++)
      bfr[n] = *(const bf16x8*)&Bl[bsel][(wc * 64 + n * 16 + fr) * 32 + cc];
    #pragma unroll
    for (int m = 0; m < 4; m++)
      #pragma unroll
      for (int n = 0; n < 4; n++)
        acc[m][n] = __builtin_amdgcn_mfma_f32_16x16x32_bf16(af[m], bfr[n], acc[m][n], 0, 0, 0);
    bsel = (bsel == 2) ? 0 : bsel + 1;
    snext = (snext == 2) ? 0 : snext + 1;
  }
#undef STAGE

  float* Cf = (float*)Cv;
  __hip_bfloat16* Cb = (__hip_bfloat16*)Cv;
  if (PARTIAL){
    const size_t pstride = (size_t)gy * 128 * Nld;
    if (OUT_BF16) Cb += (size_t)blockIdx.z * pstride;
    else          Cf += (size_t)blockIdx.z * pstride;
  }
  const int r0 = (l >> 4) * 4;
  #pragma unroll
  for (int m = 0; m < 4; m++){
    #pragma unroll
    for (int n = 0; n < 4; n++){
      int col = bn + wc * 64 + n * 16 + fr;
      if (col < Nreal){
        size_t base = (size_t)(bm + wr * 64 + m * 16 + r0) * Nld + col;
        #pragma unroll
        for (int j = 0; j < 4; j++){
          float v = acc[m][n][j];
          size_t o = base + (size_t)j * Nld;
          if (OUT_BF16) Cb[o] = __float2bfloat16(v);
          else          Cf[o] = v;
        }
      }
    }
  }
}

// ---------------- causal depthwise conv (S=3, k=4) + silu (xz bf16, stride NIP)
__global__ void k_conv_silu(const __hip_bfloat16* __restrict__ xz, const float* __restrict__ cw,
                            const float* __restrict__ cb, __hip_bfloat16* __restrict__ xc_b){
  int idx = blockIdx.x * 256 + threadIdx.x;
  if (idx >= B_SZ * KE) return;
  int ch = idx % KE;
  int b  = idx / KE;
  size_t ob = (size_t)b * SEQ * KE + ch;
  if (ch >= ED){
    __hip_bfloat16 z = __float2bfloat16(0.f);
    xc_b[ob] = z; xc_b[ob + KE] = z; xc_b[ob + 2 * KE] = z;
    return;
  }
  const __hip_bfloat16* base = xz + (size_t)b * SEQ * NIP + ch;
  float x0 = __bfloat162float(base[0]);
  float x1 = __bfloat162float(base[NIP]);
  float x2 = __bfloat162float(base[2 * NIP]);
  const float* w = cw + (size_t)ch * 4;
  float w1 = w[1], w2 = w[2], w3 = w[3];
  float bb = cb[ch];
  float s0 = silu_f(fmaf(w3, x0, bb));
  float s1 = silu_f(fmaf(w2, x0, fmaf(w3, x1, bb)));
  float s2 = silu_f(fmaf(w1, x0, fmaf(w2, x1, fmaf(w3, x2, bb))));
  xc_b[ob]          = __float2bfloat16(s0);
  xc_b[ob + KE]     = __float2bfloat16(s1);
  xc_b[ob + 2 * KE] = __float2bfloat16(s2);
}

// ---------------- x_proj split-K reduce: part[8][NBS][256] -> dbc fp32 + dbc_b bf16
__global__ __launch_bounds__(256)
void k_xred(const float* __restrict__ part, float* __restrict__ dbc,
            __hip_bfloat16* __restrict__ dbc_b){
  int idx = blockIdx.x * 256 + threadIdx.x;
  if (idx >= NBS * DBC_LD) return;
  float s = 0.f;
  #pragma unroll
  for (int p = 0; p < 8; p++) s += part[(size_t)p * NBS * DBC_LD + idx];
  dbc[idx] = s;
  int c = idx & 255, row = idx >> 8;
  if (c < KDT) dbc_b[(size_t)row * KDT + c] = __float2bfloat16(c < DTR ? s : 0.f);
}

// ---------------- lean scan: softplus(delta_b+bias) + SSM + D skip + z gate, in-place on xc_b
__global__ __launch_bounds__(256)
void k_scan2(const __hip_bfloat16* __restrict__ delta_b, const float* __restrict__ dbc,
             const float* __restrict__ dtb, const float* __restrict__ A_t,
             const float* __restrict__ Dp, const __hip_bfloat16* __restrict__ xz,
             __hip_bfloat16* __restrict__ xc_b){
  __shared__ float sB[SEQ][NSTATE], sC[SEQ][NSTATE];
  int b = blockIdx.y;
  if (threadIdx.x < SEQ * 2 * NSTATE){
    int t = threadIdx.x / (2 * NSTATE), r = threadIdx.x % (2 * NSTATE);
    float v = dbc[(size_t)(b * SEQ + t) * DBC_LD + DTR + r];
    if (r < NSTATE) sB[t][r] = v; else sC[t][r - NSTATE] = v;
  }
  __syncthreads();
  int ch = blockIdx.x * 256 + threadIdx.x;
  if (ch >= ED) return;

  float bias = dtb[ch];
  float dlt[SEQ];
  #pragma unroll
  for (int t = 0; t < SEQ; t++){
    float acc = __bfloat162float(delta_b[(size_t)(b * SEQ + t) * NDT + ch]) + bias;
    dlt[t] = (acc > 20.f) ? acc : log1pf(expf(acc));
  }

  size_t ob = (size_t)b * SEQ * KE + ch;
  float xcv[SEQ] = { __bfloat162float(xc_b[ob]),
                     __bfloat162float(xc_b[ob + KE]),
                     __bfloat162float(xc_b[ob + 2 * KE]) };
  float y[SEQ] = {0.f, 0.f, 0.f};
  #pragma unroll
  for (int n = 0; n < NSTATE; n++){
    float Av = A_t[(size_t)n * ED + ch];
    float hs = 0.f;
    #pragma unroll
    for (int t = 0; t < SEQ; t++){
      float dA = expf(dlt[t] * Av);
      hs = fmaf(dA, hs, dlt[t] * sB[t][n] * xcv[t]);
      y[t] = fmaf(hs, sC[t][n], y[t]);
    }
  }
  float dp = Dp[ch];
  const __hip_bfloat16* zbase = xz + (size_t)b * SEQ * NIP + ED + ch;
  #pragma unroll
  for (int t = 0; t < SEQ; t++){
    float z = __bfloat162float(zbase[(size_t)t * NIP]);
    float yy = fmaf(dp, xcv[t], y[t]);
    xc_b[ob + (size_t)t * KE] = __float2bfloat16(yy * silu_f(z));
  }
}

// ---------------- lm partial reduce -> logits, + stats (raw sum, sumsq) via atomics
__global__ __launch_bounds__(256)
void k_statsred(const float* __restrict__ part, float* __restrict__ logits,
                float* __restrict__ stats){
  float s = 0.f, ss = 0.f;
  for (int i = blockIdx.x * 256 + threadIdx.x; i < NBS * VOCAB; i += gridDim.x * 256){
    float v = 0.f;
    #pragma unroll
    for (int p = 0; p < 4; p++) v += part[(size_t)p * NBS * VOCAB + i];
    logits[i] = v;
    s += v; ss = fmaf(v, v, ss);
  }
  #pragma unroll
  for (int o = 32; o > 0; o >>= 1){ s += __shfl_down(s, o, 64); ss += __shfl_down(ss, o, 64); }
  __shared__ float rs[4], rss[4];
  int lane = threadIdx.x & 63, wv = threadIdx.x >> 6;
  if (lane == 0){ rs[wv] = s; rss[wv] = ss; }
  __syncthreads();
  if (threadIdx.x == 0){
    atomicAdd(&stats[0], rs[0] + rs[1] + rs[2] + rs[3]);
    atomicAdd(&stats[1], rss[0] + rss[1] + rss[2] + rss[3]);
  }
}

// ---------------- fused: proj = logits @ emb^T, BN normalize, write out[b,f,s,o]
__global__ __launch_bounds__(256)
void k_projfinal(const float* __restrict__ logits, const float* __restrict__ emb_t,
                 const float* __restrict__ sumw, const float* __restrict__ stats,
                 const float* __restrict__ bnw, const float* __restrict__ bnb,
                 const float* __restrict__ embb, float* __restrict__ out){
  __shared__ float row[VOCAB];
  int r = blockIdx.x;            // b*SEQ + s
  int o = threadIdx.x;           // 0..255
  if (o < VOCAB) row[o] = logits[(size_t)r * VOCAB + o];
  __syncthreads();
  float p = 0.f;
  #pragma unroll 8
  for (int v = 0; v < VOCAB; v++) p = fmaf(row[v], emb_t[v * 256 + o], p);
  const float invN = 1.0f / (float)(NBS * VOCAB);
  float mean = stats[0] * invN;
  float var  = stats[1] * invN - mean * mean;
  float rstd = rsqrtf(var + EPSV);
  int b = r / SEQ, s = r % SEQ;
  float sw = sumw[o];
  float base = rstd * (p - mean * sw);
  float eb = embb[o];
  #pragma unroll
  for (int f = 0; f < 5; f++){
    out[(((size_t)(b * 5 + f)) * SEQ + s) * 256 + o] = bnw[f] * base + bnb[f] * sw + eb;
  }
}

extern "C" void kernel_launch(void* const* d_in, const int* in_sizes, int n_in,
                              void* d_out, int out_size, void* d_ws, size_t ws_size,
                              hipStream_t stream) {
  const float* x          = (const float*)d_in[0];
  const float* in_proj_w  = (const float*)d_in[1];
  const float* conv_w     = (const float*)d_in[2];
  const float* conv_b     = (const float*)d_in[3];
  const float* x_proj_w   = (const float*)d_in[4];
  const float* dt_proj_w  = (const float*)d_in[5];
  const float* dt_proj_b  = (const float*)d_in[6];
  const float* A_log      = (const float*)d_in[7];
  const float* D_param    = (const float*)d_in[8];
  const float* out_proj_w = (const float*)d_in[9];
  const float* norm_w     = (const float*)d_in[10];
  const float* normf_w    = (const float*)d_in[11];
  const float* lm_head_w  = (const float*)d_in[12];
  const float* bn_w       = (const float*)d_in[13];
  const float* bn_b       = (const float*)d_in[14];
  const float* emb_w      = (const float*)d_in[15];
  const float* emb_b      = (const float*)d_in[16];

  float* ws = (float*)d_ws;
  float* h      = ws;                                   // NBS*D_MODEL
  float* dbc    = h      + (size_t)NBS * D_MODEL;       // NBS*DBC_LD
  float* logits = dbc    + (size_t)NBS * DBC_LD;        // NBS*VOCAB
  float* sumw   = logits + (size_t)NBS * VOCAB;         // 256
  float* stats  = sumw   + 256;                         // 2
  float* A_t    = stats  + 2;                           // NSTATE*ED
  float* emb_t  = A_t    + (size_t)NSTATE * ED;         // VOCAB*256
  // shared partial arena (disjoint lifetimes):
  //  xpart (8*NBS*256 f32 = 12.6MB) < opart (4*NBS*1550 bf16 = 19.05MB)
  //  < lmpart (4*NBS*128 f32 = 3.1MB)
  float* spart  = emb_t  + (size_t)VOCAB * 256;
  size_t spart_f = ((size_t)4 * NBS * D_MODEL * 2 + 3) / 4; // bf16 opart in floats (largest)
  float* xpart  = spart;
  float* lmpart = spart;
  __hip_bfloat16* opart = (__hip_bfloat16*)spart;
  __hip_bfloat16* xz_b   = (__hip_bfloat16*)(spart + spart_f); // NBS*NIP
  __hip_bfloat16* hn_b   = xz_b   + (size_t)NBS * NIP;  // NBS*KD
  __hip_bfloat16* xc_b   = hn_b   + (size_t)NBS * KD;   // NBS*KE
  __hip_bfloat16* dbc_b  = xc_b   + (size_t)NBS * KE;   // NBS*KDT
  __hip_bfloat16* dlt_b  = dbc_b  + (size_t)NBS * KDT;  // NBS*NDT
  __hip_bfloat16* ipb    = dlt_b  + (size_t)NBS * NDT;  // NIP*KD
  __hip_bfloat16* xpb    = ipb    + (size_t)NIP * KD;   // NXP*KE
  __hip_bfloat16* dtwb   = xpb    + (size_t)NXP * KE;   // NDT*KDT
  __hip_bfloat16* opb    = dtwb   + (size_t)NDT * KDT;  // NOP*KE
  __hip_bfloat16* lmb    = opb    + (size_t)NOP * KE;   // VOCAB*KD
  size_t need = (size_t)((char*)(lmb + (size_t)VOCAB * KD) - (char*)ws);
  if (ws_size < need) return;

  for (int l = 0; l < 2; l++){
    const float* ipw = in_proj_w  + (size_t)l * 2 * ED * D_MODEL;
    const float* cw  = conv_w     + (size_t)l * ED * 4;
    const float* cb  = conv_b     + (size_t)l * ED;
    const float* xpw = x_proj_w   + (size_t)l * DBC_R * ED;
    const float* dtw = dt_proj_w  + (size_t)l * ED * DTR;
    const float* dtb = dt_proj_b  + (size_t)l * ED;
    const float* al  = A_log      + (size_t)l * ED * NSTATE;
    const float* dp  = D_param    + (size_t)l * ED;
    const float* opw = out_proj_w + (size_t)l * D_MODEL * ED;
    const float* nw  = norm_w     + (size_t)l * D_MODEL;

    // per-layer prep: weight casts + A_t (+ layer0: lm cast, emb_t, sumw, stats zero)
    k_prep<<<cdiv_h(l == 0 ? PREP_N0 : PREP_N1, 256), 256, 0, stream>>>(
        ipw, xpw, dtw, opw, al, lm_head_w, emb_w,
        ipb, xpb, dtwb, opb, A_t, lmb, emb_t, sumw, stats, l == 0 ? 1 : 0);

    if (l == 0){
      k_perm_rms<<<NBS, 256, 0, stream>>>(x, nw, h, hn_b);
    } else {
      k_rms_res<<<NBS, 256, 0, stream>>>(h, opart, nw, hn_b);
    }

    // in_proj: xz_b[1536,6272](bf16) = hn_b @ ipb^T
    k_gemm3<1, true, false><<<dim3(NIP / 128, NBS / 128, 1), 256, 0, stream>>>(
        hn_b, ipb, xz_b, KD, NIP, NIP);

    k_conv_silu<<<cdiv_h(B_SZ * KE, 256), 256, 0, stream>>>(xz_b, cw, cb, xc_b);

    // x_proj (split-K 8, fp32 partials)
    k_gemm3<8, false, true><<<dim3(NXP / 128, NBS / 128, 8), 256, 0, stream>>>(
        xc_b, xpb, xpart, KE, DBC_LD, DBC_LD);
    k_xred<<<cdiv_h(NBS * DBC_LD, 256), 256, 0, stream>>>(xpart, dbc, dbc_b);

    // dt_proj: dlt_b[1536,3200](bf16) = dbc_b[1536,128] @ dtwb^T
    k_gemm3<1, true, false><<<dim3(NDT / 128, NBS / 128, 1), 256, 0, stream>>>(
        dbc_b, dtwb, dlt_b, KDT, NDT, NDT);

    k_scan2<<<dim3(cdiv_h(ED, 256), B_SZ), 256, 0, stream>>>(
        dlt_b, dbc, dtb, A_t, dp, xz_b, xc_b);

    // out_proj (split-K 4, bf16 partials)
    k_gemm3<4, true, true><<<dim3(NOP / 128, NBS / 128, 4), 256, 0, stream>>>(
        xc_b, opb, opart, KE, D_MODEL, D_MODEL);
  }

  // final: fused residual-reduce + rmsnorm, lm head (split-K 4, fp32 partials)
  k_rms_res<<<NBS, 256, 0, stream>>>(h, opart, normf_w, hn_b);
  k_gemm3<4, false, true><<<dim3(1, NBS / 128, 4), 256, 0, stream>>>(
      hn_b, lmb, lmpart, KD, VOCAB, VOCAB);
  k_statsred<<<192, 256, 0, stream>>>(lmpart, logits, stats);

  k_projfinal<<<NBS, 256, 0, stream>>>(logits, emb_t, sumw, stats,
                                       bn_w, bn_b, emb_b, (float*)d_out);
}